// Round 1
// baseline (5965.314 us; speedup 1.0000x reference)
//
#include <hip/hip_runtime.h>
#include <math.h>

#define D_MODEL 512
#define NHEAD   8
#define HEAD_DIM 64
#define BB      8
#define NN      1024
#define NS      1

__device__ __forceinline__ float gelu_exact(float x) {
    return 0.5f * x * (1.0f + erff(x * 0.70710678118654752f));
}

// C[M,N] = A[M,K] @ B[N,K]^T (+ bias[N])
// 64x64 tile, BK=16, 256 threads, 4x4 micro-tile per thread.
__global__ __launch_bounds__(256)
void gemm_bt_kernel(const float* __restrict__ A, const float* __restrict__ Bm,
                    const float* __restrict__ bias, float* __restrict__ C,
                    int M, int N, int K) {
    __shared__ float As[16][64];
    __shared__ float Bs[16][64];
    const int tid = threadIdx.x;
    const int bm = blockIdx.y * 64;
    const int bn = blockIdx.x * 64;
    const int lr = tid >> 2;          // 0..63 row within tile
    const int lk = (tid & 3) << 2;    // 0,4,8,12
    const int tm = (tid >> 4) << 2;   // 0..60
    const int tn = (tid & 15) << 2;   // 0..60
    float acc[4][4] = {};
    for (int k0 = 0; k0 < K; k0 += 16) {
        float4 av = *(const float4*)(A  + (size_t)(bm + lr) * K + k0 + lk);
        float4 bv = *(const float4*)(Bm + (size_t)(bn + lr) * K + k0 + lk);
        __syncthreads();
        As[lk+0][lr] = av.x; As[lk+1][lr] = av.y; As[lk+2][lr] = av.z; As[lk+3][lr] = av.w;
        Bs[lk+0][lr] = bv.x; Bs[lk+1][lr] = bv.y; Bs[lk+2][lr] = bv.z; Bs[lk+3][lr] = bv.w;
        __syncthreads();
        #pragma unroll
        for (int k = 0; k < 16; ++k) {
            float4 a = *(const float4*)&As[k][tm];
            float4 b = *(const float4*)&Bs[k][tn];
            acc[0][0] += a.x*b.x; acc[0][1] += a.x*b.y; acc[0][2] += a.x*b.z; acc[0][3] += a.x*b.w;
            acc[1][0] += a.y*b.x; acc[1][1] += a.y*b.y; acc[1][2] += a.y*b.z; acc[1][3] += a.y*b.w;
            acc[2][0] += a.z*b.x; acc[2][1] += a.z*b.y; acc[2][2] += a.z*b.z; acc[2][3] += a.z*b.w;
            acc[3][0] += a.w*b.x; acc[3][1] += a.w*b.y; acc[3][2] += a.w*b.z; acc[3][3] += a.w*b.w;
        }
    }
    float4 bias4 = make_float4(0.f, 0.f, 0.f, 0.f);
    if (bias) bias4 = *(const float4*)(bias + bn + tn);
    #pragma unroll
    for (int r = 0; r < 4; ++r) {
        float4 o;
        o.x = acc[r][0] + bias4.x; o.y = acc[r][1] + bias4.y;
        o.z = acc[r][2] + bias4.z; o.w = acc[r][3] + bias4.w;
        *(float4*)(C + (size_t)(bm + tm + r) * N + bn + tn) = o;
    }
}

// Fused: bias-MLP (4->32 gelu ->8) + q@k^T + softmax + p@v for one (b, i).
// qkv layout per row (token): [q(512) | k(512) | v(512)]
__global__ __launch_bounds__(256)
void attn_kernel(const float* __restrict__ qkv, const float* __restrict__ coords,
                 const unsigned char* __restrict__ mask,
                 const float* __restrict__ w1, const float* __restrict__ b1,
                 const float* __restrict__ w2, const float* __restrict__ b2,
                 const float* __restrict__ coord_scales,
                 const float* __restrict__ alpha_p,
                 float* __restrict__ attn_out) {
    const int i   = blockIdx.x;
    const int b   = blockIdx.y;
    const int tid = threadIdx.x;

    __shared__ float qs[D_MODEL];
    __shared__ float logits[NHEAD][NN];   // 32 KB
    __shared__ float w1s[32 * 4];
    __shared__ float b1s[32];
    __shared__ float w2s[NHEAD * 32];
    __shared__ float b2s[NHEAD];
    __shared__ float l_s[NHEAD];
    __shared__ float ci_s[3];

    const size_t row_i = (size_t)b * NN + i;

    // stage q (512 floats) + MLP weights into LDS
    *(float2*)&qs[tid * 2] = *(const float2*)(qkv + row_i * 1536 + tid * 2);
    if (tid < 128) w1s[tid] = w1[tid];
    if (tid < 32)  b1s[tid] = b1[tid];
    w2s[tid] = w2[tid];                   // 256 = 8*32 exactly
    if (tid < 8)   b2s[tid] = b2[tid];
    if (tid < 3)   ci_s[tid] = coords[row_i * 3 + tid] / coord_scales[tid];
    __syncthreads();

    const float alpha = alpha_p[0];
    const float scale = 0.125f;           // HEAD_DIM^-0.5
    const float cix = ci_s[0], ciy = ci_s[1], ciz = ci_s[2];
    const float isx = 1.0f / coord_scales[0];
    const float isy = 1.0f / coord_scales[1];
    const float isz = 1.0f / coord_scales[2];

    // ---- phase 1: logits[h][j] for all h, this block's 4 j's per thread ----
    for (int j = tid; j < NN; j += 256) {
        const size_t row_j = (size_t)b * NN + j;
        const float cjx = coords[row_j * 3 + 0] * isx;
        const float cjy = coords[row_j * 3 + 1] * isy;
        const float cjz = coords[row_j * 3 + 2] * isz;
        const float dx = cix - cjx, dy = ciy - cjy, dz = ciz - cjz;
        const float dist = sqrtf(dx * dx + dy * dy + dz * dz);

        float biasv[NHEAD];
        #pragma unroll
        for (int h = 0; h < NHEAD; ++h) biasv[h] = b2s[h];
        if (i >= NS && j >= NS) {
            #pragma unroll
            for (int u = 0; u < 32; ++u) {
                float hu = w1s[u * 4 + 0] * dx + w1s[u * 4 + 1] * dy +
                           w1s[u * 4 + 2] * dz + w1s[u * 4 + 3] * dist + b1s[u];
                hu = gelu_exact(hu);
                #pragma unroll
                for (int h = 0; h < NHEAD; ++h) biasv[h] += hu * w2s[h * 32 + u];
            }
        } else {
            #pragma unroll
            for (int h = 0; h < NHEAD; ++h) biasv[h] = 0.0f;
        }

        const bool masked = (mask[(size_t)b * NN + j] != 0);
        const float* krow = qkv + row_j * 1536 + 512;
        #pragma unroll
        for (int h = 0; h < NHEAD; ++h) {
            float dot = 0.0f;
            #pragma unroll
            for (int e = 0; e < HEAD_DIM; e += 4) {
                float4 kv = *(const float4*)(krow + h * 64 + e);
                float4 qv = *(const float4*)(qs + h * 64 + e);
                dot += qv.x * kv.x + qv.y * kv.y + qv.z * kv.z + qv.w * kv.w;
            }
            float logit = dot * scale + alpha * biasv[h];
            if (masked) logit = -1e30f;
            logits[h][j] = logit;
        }
    }
    __syncthreads();

    // ---- phase 2a: per-head softmax (8 heads x 32 threads each) ----
    {
        const int h = tid >> 5, lane = tid & 31;
        float mx = -3.4e38f;
        for (int j = lane; j < NN; j += 32) mx = fmaxf(mx, logits[h][j]);
        #pragma unroll
        for (int off = 16; off; off >>= 1) mx = fmaxf(mx, __shfl_down(mx, off, 32));
        mx = __shfl(mx, 0, 32);
        float sum = 0.0f;
        for (int j = lane; j < NN; j += 32) {
            float p = __expf(logits[h][j] - mx);
            logits[h][j] = p;
            sum += p;
        }
        #pragma unroll
        for (int off = 16; off; off >>= 1) sum += __shfl_down(sum, off, 32);
        if (lane == 0) l_s[h] = sum;
    }
    __syncthreads();

    // ---- phase 2b: O[h][d] = sum_j p[h][j] * v[b,h,j,d]  (coalesced v reads) ----
    const int d  = tid & 63;
    const int hh = tid >> 6;              // 0..3 -> heads hh and hh+4
    float acc0 = 0.0f, acc1 = 0.0f;
    const float* vbase = qkv + (size_t)b * NN * 1536 + 1024 + d;
    #pragma unroll 4
    for (int j = 0; j < NN; ++j) {
        const float* vr = vbase + (size_t)j * 1536;
        acc0 += logits[hh][j]     * vr[hh * 64];
        acc1 += logits[hh + 4][j] * vr[(hh + 4) * 64];
    }
    attn_out[row_i * 512 + hh * 64 + d]       = acc0 / l_s[hh];
    attn_out[row_i * 512 + (hh + 4) * 64 + d] = acc1 / l_s[hh + 4];
}

extern "C" void kernel_launch(void* const* d_in, const int* in_sizes, int n_in,
                              void* d_out, int out_size, void* d_ws, size_t ws_size,
                              hipStream_t stream) {
    const float* x        = (const float*)d_in[0];   // [8,1024,512]
    const float* coords   = (const float*)d_in[1];   // [8,1024,3]
    const unsigned char* kpm = (const unsigned char*)d_in[2]; // [8,1024] bool
    const float* qkv_w    = (const float*)d_in[3];   // [1536,512]
    const float* out_w    = (const float*)d_in[4];   // [512,512]
    const float* out_b    = (const float*)d_in[5];   // [512]
    const float* alpha    = (const float*)d_in[6];   // [1]
    const float* w1       = (const float*)d_in[7];   // [32,4]
    const float* b1       = (const float*)d_in[8];   // [32]
    const float* w2       = (const float*)d_in[9];   // [8,32]
    const float* b2       = (const float*)d_in[10];  // [8]
    const float* cscales  = (const float*)d_in[11];  // [3]
    float* out = (float*)d_out;

    const int M = BB * NN;                // 8192 tokens
    float* qkv      = (float*)d_ws;                       // 8192*1536 f32 = 50.3 MB
    float* attn_out = qkv + (size_t)M * 3 * D_MODEL;      // 8192*512  f32 = 16.8 MB

    // 1) qkv = x @ qkv_w^T
    {
        dim3 grid(3 * D_MODEL / 64, M / 64);
        gemm_bt_kernel<<<grid, 256, 0, stream>>>(x, qkv_w, nullptr, qkv,
                                                 M, 3 * D_MODEL, D_MODEL);
    }
    // 2) fused bias-MLP + attention
    {
        dim3 grid(NN, BB);
        attn_kernel<<<grid, 256, 0, stream>>>(qkv, coords, kpm, w1, b1, w2, b2,
                                              cscales, alpha, attn_out);
    }
    // 3) out = attn_out @ out_w^T + out_b
    {
        dim3 grid(D_MODEL / 64, M / 64);
        gemm_bt_kernel<<<grid, 256, 0, stream>>>(attn_out, out_w, out_b, out,
                                                 M, D_MODEL, D_MODEL);
    }
}

// Round 3
// 1990.295 us; speedup vs baseline: 2.9972x; 2.9972x over previous
//
#include <hip/hip_runtime.h>
#include <math.h>

#define D_MODEL 512
#define NHEAD   8
#define HEAD_DIM 64
#define BB      8
#define NN      1024
#define NS      1
#define TI      32
#define TJ      16

__device__ __forceinline__ float gelu_exact(float x) {
    return 0.5f * x * (1.0f + erff(x * 0.70710678118654752f));
}

// C[M,N] = A[M,K] @ B[N,K]^T (+ bias[N])  — unchanged from R1 (validated).
__global__ __launch_bounds__(256)
void gemm_bt_kernel(const float* __restrict__ A, const float* __restrict__ Bm,
                    const float* __restrict__ bias, float* __restrict__ C,
                    int M, int N, int K) {
    __shared__ float As[16][64];
    __shared__ float Bs[16][64];
    const int tid = threadIdx.x;
    const int bm = blockIdx.y * 64;
    const int bn = blockIdx.x * 64;
    const int lr = tid >> 2;
    const int lk = (tid & 3) << 2;
    const int tm = (tid >> 4) << 2;
    const int tn = (tid & 15) << 2;
    float acc[4][4] = {};
    for (int k0 = 0; k0 < K; k0 += 16) {
        float4 av = *(const float4*)(A  + (size_t)(bm + lr) * K + k0 + lk);
        float4 bv = *(const float4*)(Bm + (size_t)(bn + lr) * K + k0 + lk);
        __syncthreads();
        As[lk+0][lr] = av.x; As[lk+1][lr] = av.y; As[lk+2][lr] = av.z; As[lk+3][lr] = av.w;
        Bs[lk+0][lr] = bv.x; Bs[lk+1][lr] = bv.y; Bs[lk+2][lr] = bv.z; Bs[lk+3][lr] = bv.w;
        __syncthreads();
        #pragma unroll
        for (int k = 0; k < 16; ++k) {
            float4 a = *(const float4*)&As[k][tm];
            float4 b = *(const float4*)&Bs[k][tn];
            acc[0][0] += a.x*b.x; acc[0][1] += a.x*b.y; acc[0][2] += a.x*b.z; acc[0][3] += a.x*b.w;
            acc[1][0] += a.y*b.x; acc[1][1] += a.y*b.y; acc[1][2] += a.y*b.z; acc[1][3] += a.y*b.w;
            acc[2][0] += a.z*b.x; acc[2][1] += a.z*b.y; acc[2][2] += a.z*b.z; acc[2][3] += a.z*b.w;
            acc[3][0] += a.w*b.x; acc[3][1] += a.w*b.y; acc[3][2] += a.w*b.z; acc[3][3] += a.w*b.w;
        }
    }
    float4 bias4 = make_float4(0.f, 0.f, 0.f, 0.f);
    if (bias) bias4 = *(const float4*)(bias + bn + tn);
    #pragma unroll
    for (int r = 0; r < 4; ++r) {
        float4 o;
        o.x = acc[r][0] + bias4.x; o.y = acc[r][1] + bias4.y;
        o.z = acc[r][2] + bias4.z; o.w = acc[r][3] + bias4.w;
        *(float4*)(C + (size_t)(bm + tm + r) * N + bn + tn) = o;
    }
}

// Flash-style fused bias-MLP + attention.
// Block: TI=32 queries x 8 heads of one batch; 256 threads, tid = h*32 + il.
// LDS total ~53.5 KB (static <= 64 KB). Per-thread logits kept in registers.
__global__ __launch_bounds__(256)
void attn_kernel(const float* __restrict__ qkv, const float* __restrict__ coords,
                 const unsigned char* __restrict__ mask,
                 const float* __restrict__ w1, const float* __restrict__ b1,
                 const float* __restrict__ w2, const float* __restrict__ b2,
                 const float* __restrict__ coord_scales,
                 const float* __restrict__ alpha_p,
                 float* __restrict__ attn_out) {
    const int b   = blockIdx.y;
    const int i0  = blockIdx.x * TI;
    const int tid = threadIdx.x;
    const int h   = tid >> 5;      // 0..7
    const int il  = tid & 31;      // local query index

    __shared__ float Ks[TJ][512];        // 32 KB, K tile then V tile
    __shared__ float bias_s[TJ][TI][9];  // 18 KB (padded: conflict-free reads)
    __shared__ float w1s[128], b1s[32], w2s[256], b2s_[8];
    __shared__ float ci_s[TI][3];
    __shared__ float cj_s[TJ][3];
    __shared__ float mflag_s[TJ];

    // one-time staging: MLP weights + scaled query coords
    if (tid < 128) w1s[tid] = w1[tid];
    if (tid < 32)  b1s[tid] = b1[tid];
    w2s[tid] = w2[tid];
    if (tid < 8)   b2s_[tid] = b2[tid];
    if (tid < TI * 3)
        ci_s[tid / 3][tid % 3] =
            coords[((size_t)b * NN + i0 + tid / 3) * 3 + tid % 3] / coord_scales[tid % 3];

    // q fragment: 64 floats in registers
    const size_t row_i = (size_t)b * NN + i0 + il;
    float4 qf[16];
    #pragma unroll
    for (int t = 0; t < 16; ++t)
        qf[t] = *(const float4*)(qkv + row_i * 1536 + h * 64 + t * 4);

    float4 o[16];
    #pragma unroll
    for (int t = 0; t < 16; ++t) o[t] = make_float4(0.f, 0.f, 0.f, 0.f);
    float m_run = -INFINITY, l_run = 0.0f;
    const float alpha = alpha_p[0];
    const float scale = 0.125f;

    for (int jt = 0; jt < NN / TJ; ++jt) {
        const int j0 = jt * TJ;
        __syncthreads();  // previous iteration's PV reads of Ks done
        // ---- stage K tile (coalesced): 2048 float4 / 256 threads = 8 each ----
        #pragma unroll
        for (int f = 0; f < 8; ++f) {
            int idx = tid + f * 256;
            int j = idx >> 7, d4 = idx & 127;
            *(float4*)&Ks[j][d4 * 4] =
                *(const float4*)(qkv + ((size_t)b * NN + j0 + j) * 1536 + 512 + d4 * 4);
        }
        if (tid < TJ * 3)
            cj_s[tid / 3][tid % 3] =
                coords[((size_t)b * NN + j0 + tid / 3) * 3 + tid % 3] / coord_scales[tid % 3];
        if (tid < TJ) mflag_s[tid] = mask[(size_t)b * NN + j0 + tid] ? 1.0f : 0.0f;
        __syncthreads();

        // ---- MLP phase: 16*32 = 512 pairs / 256 threads = 2 pairs each ----
        {
            const int pj = tid >> 4;   // 0..15
            const int ib = tid & 15;
            #pragma unroll
            for (int kk = 0; kk < 2; ++kk) {
                const int i = ib + 16 * kk;
                float acc[8];
                if (i0 + i == 0 || j0 + pj == 0) {
                    #pragma unroll
                    for (int hh = 0; hh < 8; ++hh) acc[hh] = 0.0f;
                } else {
                    const float dx = ci_s[i][0] - cj_s[pj][0];
                    const float dy = ci_s[i][1] - cj_s[pj][1];
                    const float dz = ci_s[i][2] - cj_s[pj][2];
                    const float dist = sqrtf(dx * dx + dy * dy + dz * dz);
                    #pragma unroll
                    for (int hh = 0; hh < 8; ++hh) acc[hh] = b2s_[hh];
                    #pragma unroll 4
                    for (int u = 0; u < 32; ++u) {
                        float hu = w1s[u * 4 + 0] * dx + w1s[u * 4 + 1] * dy +
                                   w1s[u * 4 + 2] * dz + w1s[u * 4 + 3] * dist + b1s[u];
                        hu = gelu_exact(hu);
                        #pragma unroll
                        for (int hh = 0; hh < 8; ++hh) acc[hh] += hu * w2s[hh * 32 + u];
                    }
                }
                #pragma unroll
                for (int hh = 0; hh < 8; ++hh) bias_s[pj][i][hh] = acc[hh];
            }
        }
        __syncthreads();

        // ---- QK: logits -> registers, track running max ----
        float psr[TJ];
        float mx = m_run;
        #pragma unroll
        for (int j = 0; j < TJ; ++j) {
            float4 a = make_float4(0.f, 0.f, 0.f, 0.f);
            #pragma unroll
            for (int t = 0; t < 16; ++t) {
                float4 kv = *(const float4*)&Ks[j][h * 64 + t * 4];
                a.x += qf[t].x * kv.x; a.y += qf[t].y * kv.y;
                a.z += qf[t].z * kv.z; a.w += qf[t].w * kv.w;
            }
            float logit = ((a.x + a.y) + (a.z + a.w)) * scale + alpha * bias_s[j][il][h];
            logit = (mflag_s[j] != 0.0f) ? -1e30f : logit;
            psr[j] = logit;
            mx = fmaxf(mx, logit);
        }
        const float corr = __expf(m_run - mx);
        m_run = mx;
        l_run *= corr;
        #pragma unroll
        for (int t = 0; t < 16; ++t) {
            o[t].x *= corr; o[t].y *= corr; o[t].z *= corr; o[t].w *= corr;
        }

        __syncthreads();  // QK reads of Ks done
        // ---- stage V tile into same buffer ----
        #pragma unroll
        for (int f = 0; f < 8; ++f) {
            int idx = tid + f * 256;
            int j = idx >> 7, d4 = idx & 127;
            *(float4*)&Ks[j][d4 * 4] =
                *(const float4*)(qkv + ((size_t)b * NN + j0 + j) * 1536 + 1024 + d4 * 4);
        }
        __syncthreads();

        // ---- PV: exp + accumulate ----
        float sum = 0.0f;
        #pragma unroll
        for (int j = 0; j < TJ; ++j) {
            const float e = __expf(psr[j] - mx);
            sum += e;
            #pragma unroll
            for (int t = 0; t < 16; ++t) {
                float4 vv = *(const float4*)&Ks[j][h * 64 + t * 4];
                o[t].x += e * vv.x; o[t].y += e * vv.y;
                o[t].z += e * vv.z; o[t].w += e * vv.w;
            }
        }
        l_run += sum;
    }

    const float rinv = 1.0f / l_run;
    #pragma unroll
    for (int t = 0; t < 16; ++t) {
        float4 ov = make_float4(o[t].x * rinv, o[t].y * rinv, o[t].z * rinv, o[t].w * rinv);
        *(float4*)(attn_out + row_i * 512 + h * 64 + t * 4) = ov;
    }
}

extern "C" void kernel_launch(void* const* d_in, const int* in_sizes, int n_in,
                              void* d_out, int out_size, void* d_ws, size_t ws_size,
                              hipStream_t stream) {
    const float* x        = (const float*)d_in[0];
    const float* coords   = (const float*)d_in[1];
    const unsigned char* kpm = (const unsigned char*)d_in[2];
    const float* qkv_w    = (const float*)d_in[3];
    const float* out_w    = (const float*)d_in[4];
    const float* out_b    = (const float*)d_in[5];
    const float* alpha    = (const float*)d_in[6];
    const float* w1       = (const float*)d_in[7];
    const float* b1       = (const float*)d_in[8];
    const float* w2       = (const float*)d_in[9];
    const float* b2       = (const float*)d_in[10];
    const float* cscales  = (const float*)d_in[11];
    float* out = (float*)d_out;

    const int M = BB * NN;
    float* qkv      = (float*)d_ws;                   // 48 MiB
    float* attn_out = qkv + (size_t)M * 3 * D_MODEL;  // 16 MiB

    {
        dim3 grid(3 * D_MODEL / 64, M / 64);
        gemm_bt_kernel<<<grid, 256, 0, stream>>>(x, qkv_w, nullptr, qkv,
                                                 M, 3 * D_MODEL, D_MODEL);
    }
    {
        dim3 grid(NN / TI, BB);
        attn_kernel<<<grid, 256, 0, stream>>>(qkv, coords, kpm, w1, b1, w2, b2,
                                              cscales, alpha, attn_out);
    }
    {
        dim3 grid(D_MODEL / 64, M / 64);
        gemm_bt_kernel<<<grid, 256, 0, stream>>>(attn_out, out_w, out_b, out,
                                                 M, D_MODEL, D_MODEL);
    }
}

// Round 5
// 903.200 us; speedup vs baseline: 6.6046x; 2.2036x over previous
//
#include <hip/hip_runtime.h>
#include <math.h>

#define D_MODEL 512
#define NHEAD   8
#define HEAD_DIM 64
#define BB      8
#define NN      1024
#define NS      1
#define TI      16
#define TJ      32

typedef __attribute__((ext_vector_type(8))) short short8;
typedef __attribute__((ext_vector_type(4))) float floatx4;

__device__ __forceinline__ float gelu_exact(float x) {
    return 0.5f * x * (1.0f + erff(x * 0.70710678118654752f));
}

__device__ __forceinline__ unsigned short f2bf(float f) {
    unsigned u = __float_as_uint(f);
    u = (u + 0x7fffu + ((u >> 16) & 1u)) >> 16;   // RNE
    return (unsigned short)u;
}

// C[M,N] = A[M,K] @ B[N,K]^T (+ bias[N]) — fp32 out. Used for out-projection.
__global__ __launch_bounds__(256)
void gemm_bt_kernel(const float* __restrict__ A, const float* __restrict__ Bm,
                    const float* __restrict__ bias, float* __restrict__ C,
                    int M, int N, int K) {
    __shared__ float As[16][64];
    __shared__ float Bs[16][64];
    const int tid = threadIdx.x;
    const int bm = blockIdx.y * 64;
    const int bn = blockIdx.x * 64;
    const int lr = tid >> 2;
    const int lk = (tid & 3) << 2;
    const int tm = (tid >> 4) << 2;
    const int tn = (tid & 15) << 2;
    float acc[4][4] = {};
    for (int k0 = 0; k0 < K; k0 += 16) {
        float4 av = *(const float4*)(A  + (size_t)(bm + lr) * K + k0 + lk);
        float4 bv = *(const float4*)(Bm + (size_t)(bn + lr) * K + k0 + lk);
        __syncthreads();
        As[lk+0][lr] = av.x; As[lk+1][lr] = av.y; As[lk+2][lr] = av.z; As[lk+3][lr] = av.w;
        Bs[lk+0][lr] = bv.x; Bs[lk+1][lr] = bv.y; Bs[lk+2][lr] = bv.z; Bs[lk+3][lr] = bv.w;
        __syncthreads();
        #pragma unroll
        for (int k = 0; k < 16; ++k) {
            float4 a = *(const float4*)&As[k][tm];
            float4 b = *(const float4*)&Bs[k][tn];
            acc[0][0] += a.x*b.x; acc[0][1] += a.x*b.y; acc[0][2] += a.x*b.z; acc[0][3] += a.x*b.w;
            acc[1][0] += a.y*b.x; acc[1][1] += a.y*b.y; acc[1][2] += a.y*b.z; acc[1][3] += a.y*b.w;
            acc[2][0] += a.z*b.x; acc[2][1] += a.z*b.y; acc[2][2] += a.z*b.z; acc[2][3] += a.z*b.w;
            acc[3][0] += a.w*b.x; acc[3][1] += a.w*b.y; acc[3][2] += a.w*b.z; acc[3][3] += a.w*b.w;
        }
    }
    float4 bias4 = make_float4(0.f, 0.f, 0.f, 0.f);
    if (bias) bias4 = *(const float4*)(bias + bn + tn);
    #pragma unroll
    for (int r = 0; r < 4; ++r) {
        float4 o;
        o.x = acc[r][0] + bias4.x; o.y = acc[r][1] + bias4.y;
        o.z = acc[r][2] + bias4.z; o.w = acc[r][3] + bias4.w;
        *(float4*)(C + (size_t)(bm + tm + r) * N + bn + tn) = o;
    }
}

// QKV GEMM with fused bf16 epilogue: qkv = x @ qkv_w^T, split into
// Qb bf16 [b][tok][512] (x0.125), Kb bf16 [b][tok][512], Vt bf16 [b][512][1024].
// A 64-col tile never straddles the Q/K/V segment boundaries (512-aligned).
__global__ __launch_bounds__(256)
void gemm_qkv_kernel(const float* __restrict__ A, const float* __restrict__ Bm,
                     unsigned short* __restrict__ Qb, unsigned short* __restrict__ Kb,
                     unsigned short* __restrict__ Vt) {
    const int K = D_MODEL;
    __shared__ float As[16][64];
    __shared__ float Bs[16][64];
    const int tid = threadIdx.x;
    const int bm = blockIdx.y * 64;
    const int bn = blockIdx.x * 64;
    const int lr = tid >> 2;
    const int lk = (tid & 3) << 2;
    const int tm = (tid >> 4) << 2;
    const int tn = (tid & 15) << 2;
    float acc[4][4] = {};
    for (int k0 = 0; k0 < K; k0 += 16) {
        float4 av = *(const float4*)(A  + (size_t)(bm + lr) * K + k0 + lk);
        float4 bv = *(const float4*)(Bm + (size_t)(bn + lr) * K + k0 + lk);
        __syncthreads();
        As[lk+0][lr] = av.x; As[lk+1][lr] = av.y; As[lk+2][lr] = av.z; As[lk+3][lr] = av.w;
        Bs[lk+0][lr] = bv.x; Bs[lk+1][lr] = bv.y; Bs[lk+2][lr] = bv.z; Bs[lk+3][lr] = bv.w;
        __syncthreads();
        #pragma unroll
        for (int k = 0; k < 16; ++k) {
            float4 a = *(const float4*)&As[k][tm];
            float4 b = *(const float4*)&Bs[k][tn];
            acc[0][0] += a.x*b.x; acc[0][1] += a.x*b.y; acc[0][2] += a.x*b.z; acc[0][3] += a.x*b.w;
            acc[1][0] += a.y*b.x; acc[1][1] += a.y*b.y; acc[1][2] += a.y*b.z; acc[1][3] += a.y*b.w;
            acc[2][0] += a.z*b.x; acc[2][1] += a.z*b.y; acc[2][2] += a.z*b.z; acc[2][3] += a.z*b.w;
            acc[3][0] += a.w*b.x; acc[3][1] += a.w*b.y; acc[3][2] += a.w*b.z; acc[3][3] += a.w*b.w;
        }
    }
    const int g0 = bn + tn;       // global output column
    const int t0 = bm + tm;       // global token row
    if (g0 < 1024) {
        unsigned short* dst = (g0 < 512) ? Qb : Kb;
        const int col = (g0 < 512) ? g0 : g0 - 512;
        const float sc = (g0 < 512) ? 0.125f : 1.0f;
        #pragma unroll
        for (int r = 0; r < 4; ++r) {
            uint2 p;
            p.x = (unsigned)f2bf(acc[r][0] * sc) | ((unsigned)f2bf(acc[r][1] * sc) << 16);
            p.y = (unsigned)f2bf(acc[r][2] * sc) | ((unsigned)f2bf(acc[r][3] * sc) << 16);
            *(uint2*)(dst + (size_t)(t0 + r) * 512 + col) = p;
        }
    } else {
        const int vd  = g0 - 1024;
        const int bb  = t0 >> 10;
        const int tok = t0 & 1023;
        #pragma unroll
        for (int c = 0; c < 4; ++c) {
            uint2 p;
            p.x = (unsigned)f2bf(acc[0][c]) | ((unsigned)f2bf(acc[1][c]) << 16);
            p.y = (unsigned)f2bf(acc[2][c]) | ((unsigned)f2bf(acc[3][c]) << 16);
            *(uint2*)(Vt + ((size_t)bb * 512 + vd + c) * NN + tok) = p;
        }
    }
}

// MFMA flash attention. Block = (b, 16 queries, all 8 heads); 256 thr = 4 waves,
// wave w handles heads 2w,2w+1. K/V fragments direct from global (L2/L3).
// MLP bias shared across heads via LDS; P round-trips LDS in bf16.
// 3 barriers/iter: C (coords staged), A (bias ready), B (tile consumed).
__global__ __launch_bounds__(256)
void attn_kernel(const unsigned short* __restrict__ Qb,
                 const unsigned short* __restrict__ Kb,
                 const unsigned short* __restrict__ Vt,
                 const float* __restrict__ coords,
                 const unsigned char* __restrict__ mask,
                 const float* __restrict__ w1, const float* __restrict__ b1,
                 const float* __restrict__ w2, const float* __restrict__ b2,
                 const float* __restrict__ coord_scales,
                 const float* __restrict__ alpha_p,
                 float* __restrict__ attn_out) {
    const int b   = blockIdx.y;
    const int i0  = blockIdx.x * TI;
    const int tid = threadIdx.x;
    const int wv  = tid >> 6;
    const int lane = tid & 63;
    const int quad = lane >> 4;
    const int ln   = lane & 15;
    const int h0   = wv * 2;

    __shared__ float bias_s[TI][TJ][9];                 // 18.4 KB, [i][j][h(+pad)]
    __shared__ __align__(16) unsigned short ps[NHEAD][TI][40];  // 10 KB  P bf16
    __shared__ float w1s[128], b1s[32], w2s[256], b2s_[8];
    __shared__ float ci_s[TI][3];
    __shared__ float cj_s[TJ][3];
    __shared__ float mflag_s[TJ];

    if (tid < 128) w1s[tid] = w1[tid];
    if (tid < 32)  b1s[tid] = b1[tid];
    w2s[tid] = w2[tid];
    if (tid < 8)   b2s_[tid] = b2[tid];
    if (tid < TI * 3)
        ci_s[tid / 3][tid % 3] =
            coords[((size_t)b * NN + i0 + tid / 3) * 3 + tid % 3] / coord_scales[tid % 3];

    // Q A-fragments (bf16, pre-scaled by 0.125): A[m=ln][k=quad*8+jj]
    short8 qf[2][2];
    #pragma unroll
    for (int hh = 0; hh < 2; ++hh)
        #pragma unroll
        for (int kd = 0; kd < 2; ++kd)
            qf[hh][kd] = *(const short8*)(Qb + ((size_t)b * NN + i0 + ln) * 512
                                          + (h0 + hh) * 64 + kd * 32 + quad * 8);

    floatx4 oacc[2][4];
    #pragma unroll
    for (int hh = 0; hh < 2; ++hh)
        #pragma unroll
        for (int nd = 0; nd < 4; ++nd)
            oacc[hh][nd] = (floatx4){0.f, 0.f, 0.f, 0.f};
    float m_run[2][4], l_run[2][4];
    #pragma unroll
    for (int hh = 0; hh < 2; ++hh)
        #pragma unroll
        for (int r = 0; r < 4; ++r) { m_run[hh][r] = -INFINITY; l_run[hh][r] = 0.f; }

    const float alpha = alpha_p[0];
    const int mi = tid & 15;       // MLP pair mapping
    const int mj = tid >> 4;

    for (int jt = 0; jt < NN / TJ; ++jt) {
        const int j0 = jt * TJ;
        if (tid < TJ * 3)
            cj_s[tid / 3][tid % 3] =
                coords[((size_t)b * NN + j0 + tid / 3) * 3 + tid % 3] / coord_scales[tid % 3];
        if (tid < TJ) mflag_s[tid] = mask[(size_t)b * NN + j0 + tid] ? 1.0f : 0.0f;
        __syncthreads();   // barrier C: cj_s/mflag_s ready for ALL threads

        // ---- MLP: 16x32 pairs / 256 threads = 2 each ----
        #pragma unroll
        for (int kk = 0; kk < 2; ++kk) {
            const int j = mj + 16 * kk;
            float acc[8];
            if (i0 + mi < NS || j0 + j < NS) {
                #pragma unroll
                for (int hh = 0; hh < 8; ++hh) acc[hh] = 0.0f;
            } else {
                const float dx = ci_s[mi][0] - cj_s[j][0];
                const float dy = ci_s[mi][1] - cj_s[j][1];
                const float dz = ci_s[mi][2] - cj_s[j][2];
                const float dist = sqrtf(dx * dx + dy * dy + dz * dz);
                #pragma unroll
                for (int hh = 0; hh < 8; ++hh) acc[hh] = b2s_[hh];
                #pragma unroll 4
                for (int u = 0; u < 32; ++u) {
                    float hu = w1s[u * 4 + 0] * dx + w1s[u * 4 + 1] * dy +
                               w1s[u * 4 + 2] * dz + w1s[u * 4 + 3] * dist + b1s[u];
                    hu = gelu_exact(hu);
                    #pragma unroll
                    for (int hh = 0; hh < 8; ++hh) acc[hh] += hu * w2s[hh * 32 + u];
                }
            }
            #pragma unroll
            for (int hh = 0; hh < 8; ++hh) bias_s[mi][j][hh] = acc[hh];
        }
        __syncthreads();   // barrier A: bias_s ready

        // ---- QK mfma + bias + online softmax + P->LDS ----
        const float mf0 = mflag_s[ln], mf1 = mflag_s[16 + ln];
        #pragma unroll
        for (int hh = 0; hh < 2; ++hh) {
            const int h = h0 + hh;
            const unsigned short* kbase = Kb + ((size_t)b * NN + j0) * 512 + h * 64;
            short8 k00 = *(const short8*)(kbase + (size_t)ln * 512 + quad * 8);
            short8 k01 = *(const short8*)(kbase + (size_t)ln * 512 + 32 + quad * 8);
            short8 k10 = *(const short8*)(kbase + (size_t)(16 + ln) * 512 + quad * 8);
            short8 k11 = *(const short8*)(kbase + (size_t)(16 + ln) * 512 + 32 + quad * 8);
            floatx4 s0 = (floatx4){0.f, 0.f, 0.f, 0.f};
            floatx4 s1 = (floatx4){0.f, 0.f, 0.f, 0.f};
            s0 = __builtin_amdgcn_mfma_f32_16x16x32_bf16(qf[hh][0], k00, s0, 0, 0, 0);
            s0 = __builtin_amdgcn_mfma_f32_16x16x32_bf16(qf[hh][1], k01, s0, 0, 0, 0);
            s1 = __builtin_amdgcn_mfma_f32_16x16x32_bf16(qf[hh][0], k10, s1, 0, 0, 0);
            s1 = __builtin_amdgcn_mfma_f32_16x16x32_bf16(qf[hh][1], k11, s1, 0, 0, 0);
            #pragma unroll
            for (int r = 0; r < 4; ++r) {
                const int row = quad * 4 + r;
                float v0 = s0[r] + alpha * bias_s[row][ln][h];
                float v1 = s1[r] + alpha * bias_s[row][16 + ln][h];
                v0 = (mf0 != 0.0f) ? -1e30f : v0;
                v1 = (mf1 != 0.0f) ? -1e30f : v1;
                float mx = fmaxf(v0, v1);
                #pragma unroll
                for (int off = 1; off < 16; off <<= 1)
                    mx = fmaxf(mx, __shfl_xor(mx, off, 64));
                const float mnew = fmaxf(m_run[hh][r], mx);
                const float corr = __expf(m_run[hh][r] - mnew);
                m_run[hh][r] = mnew;
                const float e0 = __expf(v0 - mnew);
                const float e1 = __expf(v1 - mnew);
                float rs = e0 + e1;
                #pragma unroll
                for (int off = 1; off < 16; off <<= 1)
                    rs += __shfl_xor(rs, off, 64);
                l_run[hh][r] = l_run[hh][r] * corr + rs;
                #pragma unroll
                for (int nd = 0; nd < 4; ++nd) oacc[hh][nd][r] *= corr;
                ps[h][row][ln]      = f2bf(e0);
                ps[h][row][16 + ln] = f2bf(e1);
            }
        }
        __syncthreads();   // barrier B: tile fully consumed (bias_s/mflag_s/cj_s free)

        // ---- PV mfma: A = P (from LDS), B = Vt fragments (global) ----
        #pragma unroll
        for (int hh = 0; hh < 2; ++hh) {
            const int h = h0 + hh;
            short8 pa = *(const short8*)&ps[h][ln][quad * 8];
            const unsigned short* vbase = Vt + ((size_t)b * 512 + h * 64) * NN + j0 + quad * 8;
            #pragma unroll
            for (int nd = 0; nd < 4; ++nd) {
                short8 vf = *(const short8*)(vbase + (size_t)(nd * 16 + ln) * NN);
                oacc[hh][nd] = __builtin_amdgcn_mfma_f32_16x16x32_bf16(pa, vf, oacc[hh][nd], 0, 0, 0);
            }
        }
    }

    // epilogue: O /= l, store fp32
    #pragma unroll
    for (int hh = 0; hh < 2; ++hh) {
        float rl[4];
        #pragma unroll
        for (int r = 0; r < 4; ++r) rl[r] = 1.0f / l_run[hh][r];
        #pragma unroll
        for (int nd = 0; nd < 4; ++nd)
            #pragma unroll
            for (int r = 0; r < 4; ++r)
                attn_out[((size_t)b * NN + i0 + quad * 4 + r) * 512
                         + (h0 + hh) * 64 + nd * 16 + ln] = oacc[hh][nd][r] * rl[r];
    }
}

extern "C" void kernel_launch(void* const* d_in, const int* in_sizes, int n_in,
                              void* d_out, int out_size, void* d_ws, size_t ws_size,
                              hipStream_t stream) {
    const float* x        = (const float*)d_in[0];
    const float* coords   = (const float*)d_in[1];
    const unsigned char* kpm = (const unsigned char*)d_in[2];
    const float* qkv_w    = (const float*)d_in[3];
    const float* out_w    = (const float*)d_in[4];
    const float* out_b    = (const float*)d_in[5];
    const float* alpha    = (const float*)d_in[6];
    const float* w1       = (const float*)d_in[7];
    const float* b1       = (const float*)d_in[8];
    const float* w2       = (const float*)d_in[9];
    const float* b2       = (const float*)d_in[10];
    const float* cscales  = (const float*)d_in[11];
    float* out = (float*)d_out;

    const int M = BB * NN;
    // workspace: Qb/Kb/Vt bf16 (3 x 8.39 MB) + attn_out fp32 (16.8 MB) = 42 MB
    unsigned short* Qb = (unsigned short*)d_ws;
    unsigned short* Kb = Qb + (size_t)M * D_MODEL;
    unsigned short* Vt = Kb + (size_t)M * D_MODEL;
    float* attn_out = (float*)(Vt + (size_t)M * D_MODEL);

    {
        dim3 grid(3 * D_MODEL / 64, M / 64);
        gemm_qkv_kernel<<<grid, 256, 0, stream>>>(x, qkv_w, Qb, Kb, Vt);
    }
    {
        dim3 grid(NN / TI, BB);
        attn_kernel<<<grid, 256, 0, stream>>>(Qb, Kb, Vt, coords, kpm, w1, b1, w2, b2,
                                              cscales, alpha, attn_out);
    }
    {
        dim3 grid(D_MODEL / 64, M / 64);
        gemm_bt_kernel<<<grid, 256, 0, stream>>>(attn_out, out_w, out_b, out,
                                                 M, D_MODEL, D_MODEL);
    }
}

// Round 6
// 739.899 us; speedup vs baseline: 8.0623x; 1.2207x over previous
//
#include <hip/hip_runtime.h>
#include <math.h>

#define D_MODEL 512
#define NHEAD   8
#define HEAD_DIM 64
#define BB      8
#define NN      1024
#define NS      1
#define TI      16
#define TJ      32
#define FIX_M   10.0f

typedef __attribute__((ext_vector_type(8))) short short8;
typedef __attribute__((ext_vector_type(4))) float floatx4;

// Branch-free gelu: erf via Abramowitz-Stegun 7.1.26 (|err| <= 1.5e-7).
__device__ __forceinline__ float gelu_fast(float x) {
    const float s = x * 0.70710678118654752f;
    const float u = fabsf(s);
    const float t = __builtin_amdgcn_rcpf(fmaf(0.3275911f, u, 1.0f));
    float p = fmaf(1.061405429f, t, -1.453152027f);
    p = fmaf(p, t, 1.421413741f);
    p = fmaf(p, t, -0.284496736f);
    p = fmaf(p, t, 0.254829592f);
    p = p * t;
    const float e = __expf(-u * u);
    float erf_u = fmaf(-p, e, 1.0f);
    erf_u = copysignf(erf_u, s);
    return 0.5f * x * (1.0f + erf_u);
}

__device__ __forceinline__ unsigned short f2bf(float f) {
    unsigned u = __float_as_uint(f);
    u = (u + 0x7fffu + ((u >> 16) & 1u)) >> 16;   // RNE
    return (unsigned short)u;
}

// C[M,N] = A[M,K] @ B[N,K]^T (+ bias[N]) — fp32 out (out-projection).
__global__ __launch_bounds__(256)
void gemm_bt_kernel(const float* __restrict__ A, const float* __restrict__ Bm,
                    const float* __restrict__ bias, float* __restrict__ C,
                    int M, int N, int K) {
    __shared__ float As[16][64];
    __shared__ float Bs[16][64];
    const int tid = threadIdx.x;
    const int bm = blockIdx.y * 64;
    const int bn = blockIdx.x * 64;
    const int lr = tid >> 2;
    const int lk = (tid & 3) << 2;
    const int tm = (tid >> 4) << 2;
    const int tn = (tid & 15) << 2;
    float acc[4][4] = {};
    for (int k0 = 0; k0 < K; k0 += 16) {
        float4 av = *(const float4*)(A  + (size_t)(bm + lr) * K + k0 + lk);
        float4 bv = *(const float4*)(Bm + (size_t)(bn + lr) * K + k0 + lk);
        __syncthreads();
        As[lk+0][lr] = av.x; As[lk+1][lr] = av.y; As[lk+2][lr] = av.z; As[lk+3][lr] = av.w;
        Bs[lk+0][lr] = bv.x; Bs[lk+1][lr] = bv.y; Bs[lk+2][lr] = bv.z; Bs[lk+3][lr] = bv.w;
        __syncthreads();
        #pragma unroll
        for (int k = 0; k < 16; ++k) {
            float4 a = *(const float4*)&As[k][tm];
            float4 b = *(const float4*)&Bs[k][tn];
            acc[0][0] += a.x*b.x; acc[0][1] += a.x*b.y; acc[0][2] += a.x*b.z; acc[0][3] += a.x*b.w;
            acc[1][0] += a.y*b.x; acc[1][1] += a.y*b.y; acc[1][2] += a.y*b.z; acc[1][3] += a.y*b.w;
            acc[2][0] += a.z*b.x; acc[2][1] += a.z*b.y; acc[2][2] += a.z*b.z; acc[2][3] += a.z*b.w;
            acc[3][0] += a.w*b.x; acc[3][1] += a.w*b.y; acc[3][2] += a.w*b.z; acc[3][3] += a.w*b.w;
        }
    }
    float4 bias4 = make_float4(0.f, 0.f, 0.f, 0.f);
    if (bias) bias4 = *(const float4*)(bias + bn + tn);
    #pragma unroll
    for (int r = 0; r < 4; ++r) {
        float4 o;
        o.x = acc[r][0] + bias4.x; o.y = acc[r][1] + bias4.y;
        o.z = acc[r][2] + bias4.z; o.w = acc[r][3] + bias4.w;
        *(float4*)(C + (size_t)(bm + tm + r) * N + bn + tn) = o;
    }
}

// QKV GEMM with fused bf16 epilogue (validated R5).
__global__ __launch_bounds__(256)
void gemm_qkv_kernel(const float* __restrict__ A, const float* __restrict__ Bm,
                     unsigned short* __restrict__ Qb, unsigned short* __restrict__ Kb,
                     unsigned short* __restrict__ Vt) {
    const int K = D_MODEL;
    __shared__ float As[16][64];
    __shared__ float Bs[16][64];
    const int tid = threadIdx.x;
    const int bm = blockIdx.y * 64;
    const int bn = blockIdx.x * 64;
    const int lr = tid >> 2;
    const int lk = (tid & 3) << 2;
    const int tm = (tid >> 4) << 2;
    const int tn = (tid & 15) << 2;
    float acc[4][4] = {};
    for (int k0 = 0; k0 < K; k0 += 16) {
        float4 av = *(const float4*)(A  + (size_t)(bm + lr) * K + k0 + lk);
        float4 bv = *(const float4*)(Bm + (size_t)(bn + lr) * K + k0 + lk);
        __syncthreads();
        As[lk+0][lr] = av.x; As[lk+1][lr] = av.y; As[lk+2][lr] = av.z; As[lk+3][lr] = av.w;
        Bs[lk+0][lr] = bv.x; Bs[lk+1][lr] = bv.y; Bs[lk+2][lr] = bv.z; Bs[lk+3][lr] = bv.w;
        __syncthreads();
        #pragma unroll
        for (int k = 0; k < 16; ++k) {
            float4 a = *(const float4*)&As[k][tm];
            float4 b = *(const float4*)&Bs[k][tn];
            acc[0][0] += a.x*b.x; acc[0][1] += a.x*b.y; acc[0][2] += a.x*b.z; acc[0][3] += a.x*b.w;
            acc[1][0] += a.y*b.x; acc[1][1] += a.y*b.y; acc[1][2] += a.y*b.z; acc[1][3] += a.y*b.w;
            acc[2][0] += a.z*b.x; acc[2][1] += a.z*b.y; acc[2][2] += a.z*b.z; acc[2][3] += a.z*b.w;
            acc[3][0] += a.w*b.x; acc[3][1] += a.w*b.y; acc[3][2] += a.w*b.z; acc[3][3] += a.w*b.w;
        }
    }
    const int g0 = bn + tn;
    const int t0 = bm + tm;
    if (g0 < 1024) {
        unsigned short* dst = (g0 < 512) ? Qb : Kb;
        const int col = (g0 < 512) ? g0 : g0 - 512;
        const float sc = (g0 < 512) ? 0.125f : 1.0f;
        #pragma unroll
        for (int r = 0; r < 4; ++r) {
            uint2 p;
            p.x = (unsigned)f2bf(acc[r][0] * sc) | ((unsigned)f2bf(acc[r][1] * sc) << 16);
            p.y = (unsigned)f2bf(acc[r][2] * sc) | ((unsigned)f2bf(acc[r][3] * sc) << 16);
            *(uint2*)(dst + (size_t)(t0 + r) * 512 + col) = p;
        }
    } else {
        const int vd  = g0 - 1024;
        const int bb  = t0 >> 10;
        const int tok = t0 & 1023;
        #pragma unroll
        for (int c = 0; c < 4; ++c) {
            uint2 p;
            p.x = (unsigned)f2bf(acc[0][c]) | ((unsigned)f2bf(acc[1][c]) << 16);
            p.y = (unsigned)f2bf(acc[2][c]) | ((unsigned)f2bf(acc[3][c]) << 16);
            *(uint2*)(Vt + ((size_t)bb * 512 + vd + c) * NN + tok) = p;
        }
    }
}

// MFMA flash attention, fixed-shift softmax (no per-tile online rescale).
// Block = (b, 16 queries, 8 heads); 4 waves, wave wv -> heads 2wv,2wv+1.
// bias_s uses manual stride 291 (== 3 mod 32) to scatter banks.
#define BIAS_IDX(i, j, h) ((i) * 291 + (j) * 9 + (h))
__global__ __launch_bounds__(256)
void attn_kernel(const unsigned short* __restrict__ Qb,
                 const unsigned short* __restrict__ Kb,
                 const unsigned short* __restrict__ Vt,
                 const float* __restrict__ coords,
                 const unsigned char* __restrict__ mask,
                 const float* __restrict__ w1, const float* __restrict__ b1,
                 const float* __restrict__ w2, const float* __restrict__ b2,
                 const float* __restrict__ coord_scales,
                 const float* __restrict__ alpha_p,
                 float* __restrict__ attn_out) {
    const int b   = blockIdx.y;
    const int i0  = blockIdx.x * TI;
    const int tid = threadIdx.x;
    const int wv  = tid >> 6;
    const int lane = tid & 63;
    const int quad = lane >> 4;
    const int ln   = lane & 15;
    const int h0   = wv * 2;

    __shared__ float bias_s[TI * 291 + 9];              // 18.6 KB, scattered banks
    __shared__ __align__(16) unsigned short ps[NHEAD][TI][40];  // 10 KB  P bf16
    __shared__ float w1s[128], b1s[32], w2s[256], b2s_[8];
    __shared__ float ci_s[TI][3];
    __shared__ float cj_s[TJ][3];
    __shared__ float mflag_s[TJ];

    if (tid < 128) w1s[tid] = w1[tid];
    if (tid < 32)  b1s[tid] = b1[tid];
    w2s[tid] = w2[tid];
    if (tid < 8)   b2s_[tid] = b2[tid];
    if (tid < TI * 3)
        ci_s[tid / 3][tid % 3] =
            coords[((size_t)b * NN + i0 + tid / 3) * 3 + tid % 3] / coord_scales[tid % 3];

    // Q A-fragments (bf16, pre-scaled by 0.125): A[m=ln][k=quad*8+jj]
    short8 qf[2][2];
    #pragma unroll
    for (int hh = 0; hh < 2; ++hh)
        #pragma unroll
        for (int kd = 0; kd < 2; ++kd)
            qf[hh][kd] = *(const short8*)(Qb + ((size_t)b * NN + i0 + ln) * 512
                                          + (h0 + hh) * 64 + kd * 32 + quad * 8);

    floatx4 oacc[2][4];
    #pragma unroll
    for (int hh = 0; hh < 2; ++hh)
        #pragma unroll
        for (int nd = 0; nd < 4; ++nd)
            oacc[hh][nd] = (floatx4){0.f, 0.f, 0.f, 0.f};
    float l_part[2][4];
    #pragma unroll
    for (int hh = 0; hh < 2; ++hh)
        #pragma unroll
        for (int r = 0; r < 4; ++r) l_part[hh][r] = 0.f;

    const float alpha = alpha_p[0];
    const int mi = tid >> 4;       // MLP: thread's query index (0..15)
    const int mj = tid & 15;       // MLP: thread's j base (lanes vary j -> no conflicts)

    for (int jt = 0; jt < NN / TJ; ++jt) {
        const int j0 = jt * TJ;
        if (tid < TJ * 3)
            cj_s[tid / 3][tid % 3] =
                coords[((size_t)b * NN + j0 + tid / 3) * 3 + tid % 3] / coord_scales[tid % 3];
        if (tid < TJ) mflag_s[tid] = mask[(size_t)b * NN + j0 + tid] ? 1.0f : 0.0f;
        __syncthreads();   // barrier C: cj_s/mflag_s ready

        // ---- MLP: 2 pairs per thread, same i, j = mj and mj+16 ----
        #pragma unroll
        for (int kk = 0; kk < 2; ++kk) {
            const int j = mj + 16 * kk;
            float acc[8];
            if (i0 + mi < NS || j0 + j < NS) {
                #pragma unroll
                for (int hh = 0; hh < 8; ++hh) acc[hh] = 0.0f;
            } else {
                const float dx = ci_s[mi][0] - cj_s[j][0];
                const float dy = ci_s[mi][1] - cj_s[j][1];
                const float dz = ci_s[mi][2] - cj_s[j][2];
                const float dist = sqrtf(dx * dx + dy * dy + dz * dz);
                #pragma unroll
                for (int hh = 0; hh < 8; ++hh) acc[hh] = b2s_[hh];
                #pragma unroll 4
                for (int u = 0; u < 32; ++u) {
                    float hu = w1s[u * 4 + 0] * dx + w1s[u * 4 + 1] * dy +
                               w1s[u * 4 + 2] * dz + w1s[u * 4 + 3] * dist + b1s[u];
                    hu = gelu_fast(hu);
                    #pragma unroll
                    for (int hh = 0; hh < 8; ++hh) acc[hh] += hu * w2s[hh * 32 + u];
                }
            }
            #pragma unroll
            for (int hh = 0; hh < 8; ++hh) bias_s[BIAS_IDX(mi, j, hh)] = acc[hh];
        }
        __syncthreads();   // barrier A: bias_s ready

        // ---- QK mfma + bias + exp(v - FIX_M) -> P (LDS, bf16) ----
        const float mf0 = mflag_s[ln], mf1 = mflag_s[16 + ln];
        #pragma unroll
        for (int hh = 0; hh < 2; ++hh) {
            const int h = h0 + hh;
            const unsigned short* kbase = Kb + ((size_t)b * NN + j0) * 512 + h * 64;
            short8 k00 = *(const short8*)(kbase + (size_t)ln * 512 + quad * 8);
            short8 k01 = *(const short8*)(kbase + (size_t)ln * 512 + 32 + quad * 8);
            short8 k10 = *(const short8*)(kbase + (size_t)(16 + ln) * 512 + quad * 8);
            short8 k11 = *(const short8*)(kbase + (size_t)(16 + ln) * 512 + 32 + quad * 8);
            floatx4 s0 = (floatx4){0.f, 0.f, 0.f, 0.f};
            floatx4 s1 = (floatx4){0.f, 0.f, 0.f, 0.f};
            s0 = __builtin_amdgcn_mfma_f32_16x16x32_bf16(qf[hh][0], k00, s0, 0, 0, 0);
            s0 = __builtin_amdgcn_mfma_f32_16x16x32_bf16(qf[hh][1], k01, s0, 0, 0, 0);
            s1 = __builtin_amdgcn_mfma_f32_16x16x32_bf16(qf[hh][0], k10, s1, 0, 0, 0);
            s1 = __builtin_amdgcn_mfma_f32_16x16x32_bf16(qf[hh][1], k11, s1, 0, 0, 0);
            #pragma unroll
            for (int r = 0; r < 4; ++r) {
                const int row = quad * 4 + r;
                float v0 = s0[r] + alpha * bias_s[BIAS_IDX(row, ln, h)];
                float v1 = s1[r] + alpha * bias_s[BIAS_IDX(row, 16 + ln, h)];
                v0 = (mf0 != 0.0f) ? -1e30f : v0;
                v1 = (mf1 != 0.0f) ? -1e30f : v1;
                const float e0 = __expf(v0 - FIX_M);
                const float e1 = __expf(v1 - FIX_M);
                l_part[hh][r] += e0 + e1;
                ps[h][row][ln]      = f2bf(e0);
                ps[h][row][16 + ln] = f2bf(e1);
            }
        }
        __syncthreads();   // barrier B: tile consumed, P ready

        // ---- PV mfma: A = P (LDS), B = Vt fragments (global) ----
        #pragma unroll
        for (int hh = 0; hh < 2; ++hh) {
            const int h = h0 + hh;
            short8 pa = *(const short8*)&ps[h][ln][quad * 8];
            const unsigned short* vbase = Vt + ((size_t)b * 512 + h * 64) * NN + j0 + quad * 8;
            #pragma unroll
            for (int nd = 0; nd < 4; ++nd) {
                short8 vf = *(const short8*)(vbase + (size_t)(nd * 16 + ln) * NN);
                oacc[hh][nd] = __builtin_amdgcn_mfma_f32_16x16x32_bf16(pa, vf, oacc[hh][nd], 0, 0, 0);
            }
        }
    }

    // epilogue: reduce l over the 16 lanes holding each row, O /= l, store
    #pragma unroll
    for (int hh = 0; hh < 2; ++hh) {
        float rl[4];
        #pragma unroll
        for (int r = 0; r < 4; ++r) {
            float l = l_part[hh][r];
            l += __shfl_xor(l, 1, 64);
            l += __shfl_xor(l, 2, 64);
            l += __shfl_xor(l, 4, 64);
            l += __shfl_xor(l, 8, 64);
            rl[r] = 1.0f / l;
        }
        #pragma unroll
        for (int nd = 0; nd < 4; ++nd)
            #pragma unroll
            for (int r = 0; r < 4; ++r)
                attn_out[((size_t)b * NN + i0 + quad * 4 + r) * 512
                         + (h0 + hh) * 64 + nd * 16 + ln] = oacc[hh][nd][r] * rl[r];
    }
}

extern "C" void kernel_launch(void* const* d_in, const int* in_sizes, int n_in,
                              void* d_out, int out_size, void* d_ws, size_t ws_size,
                              hipStream_t stream) {
    const float* x        = (const float*)d_in[0];
    const float* coords   = (const float*)d_in[1];
    const unsigned char* kpm = (const unsigned char*)d_in[2];
    const float* qkv_w    = (const float*)d_in[3];
    const float* out_w    = (const float*)d_in[4];
    const float* out_b    = (const float*)d_in[5];
    const float* alpha    = (const float*)d_in[6];
    const float* w1       = (const float*)d_in[7];
    const float* b1       = (const float*)d_in[8];
    const float* w2       = (const float*)d_in[9];
    const float* b2       = (const float*)d_in[10];
    const float* cscales  = (const float*)d_in[11];
    float* out = (float*)d_out;

    const int M = BB * NN;
    unsigned short* Qb = (unsigned short*)d_ws;
    unsigned short* Kb = Qb + (size_t)M * D_MODEL;
    unsigned short* Vt = Kb + (size_t)M * D_MODEL;
    float* attn_out = (float*)(Vt + (size_t)M * D_MODEL);

    {
        dim3 grid(3 * D_MODEL / 64, M / 64);
        gemm_qkv_kernel<<<grid, 256, 0, stream>>>(x, qkv_w, Qb, Kb, Vt);
    }
    {
        dim3 grid(NN / TI, BB);
        attn_kernel<<<grid, 256, 0, stream>>>(Qb, Kb, Vt, coords, kpm, w1, b1, w2, b2,
                                              cscales, alpha, attn_out);
    }
    {
        dim3 grid(D_MODEL / 64, M / 64);
        gemm_bt_kernel<<<grid, 256, 0, stream>>>(attn_out, out_w, out_b, out,
                                                 M, D_MODEL, D_MODEL);
    }
}

// Round 7
// 504.514 us; speedup vs baseline: 11.8239x; 1.4666x over previous
//
#include <hip/hip_runtime.h>
#include <math.h>

#define D_MODEL 512
#define NHEAD   8
#define HEAD_DIM 64
#define BB      8
#define NN      1024
#define NS      1
#define TI      16
#define TJ      32
#define FIX_M   10.0f
#define GSTRIDE 40   // LDS row stride (shorts) for MFMA gemm tiles: 80B, 16B-aligned

typedef __attribute__((ext_vector_type(8))) short short8;
typedef __attribute__((ext_vector_type(4))) float floatx4;

// Branch-free gelu: erf via Abramowitz-Stegun 7.1.26 (|err| <= 1.5e-7).
__device__ __forceinline__ float gelu_fast(float x) {
    const float s = x * 0.70710678118654752f;
    const float u = fabsf(s);
    const float t = __builtin_amdgcn_rcpf(fmaf(0.3275911f, u, 1.0f));
    float p = fmaf(1.061405429f, t, -1.453152027f);
    p = fmaf(p, t, 1.421413741f);
    p = fmaf(p, t, -0.284496736f);
    p = fmaf(p, t, 0.254829592f);
    p = p * t;
    const float e = __expf(-u * u);
    float erf_u = fmaf(-p, e, 1.0f);
    erf_u = copysignf(erf_u, s);
    return 0.5f * x * (1.0f + erf_u);
}

__device__ __forceinline__ unsigned short f2bf(float f) {
    unsigned u = __float_as_uint(f);
    u = (u + 0x7fffu + ((u >> 16) & 1u)) >> 16;   // RNE
    return (unsigned short)u;
}

__device__ __forceinline__ uint2 pack4bf(float a, float b, float c, float d) {
    uint2 p;
    p.x = (unsigned)f2bf(a) | ((unsigned)f2bf(b) << 16);
    p.y = (unsigned)f2bf(c) | ((unsigned)f2bf(d) << 16);
    return p;
}

// ---------------- bf16 MFMA GEMM: qkv = x @ qkv_w^T, fused bf16 epilogue ----
// 128x128 tile, BK=32, 256 thr = 4 waves (2x2 of 64x64). A,B fp32 -> bf16 in staging.
__global__ __launch_bounds__(256)
void gemm_qkv_mfma(const float* __restrict__ A, const float* __restrict__ Bm,
                   unsigned short* __restrict__ Qb, unsigned short* __restrict__ Kb,
                   unsigned short* __restrict__ Vt) {
    __shared__ __align__(16) unsigned short As[128 * GSTRIDE];
    __shared__ __align__(16) unsigned short Bs[128 * GSTRIDE];
    const int tid = threadIdx.x;
    const int bm = blockIdx.y * 128;
    const int bn = blockIdx.x * 128;
    const int wv = tid >> 6, lane = tid & 63, quad = lane >> 4, ln = lane & 15;
    const int wm = (wv >> 1) * 64, wn = (wv & 1) * 64;

    floatx4 acc[4][4];
    #pragma unroll
    for (int i = 0; i < 4; ++i)
        #pragma unroll
        for (int j = 0; j < 4; ++j) acc[i][j] = (floatx4){0.f, 0.f, 0.f, 0.f};

    for (int k0 = 0; k0 < 512; k0 += 32) {
        __syncthreads();
        #pragma unroll
        for (int t = 0; t < 4; ++t) {
            const int c = tid + t * 256;
            const int row = c >> 3, kc = (c & 7) * 4;
            float4 v = *(const float4*)(A + (size_t)(bm + row) * 512 + k0 + kc);
            *(uint2*)&As[row * GSTRIDE + kc] = pack4bf(v.x, v.y, v.z, v.w);
            float4 w = *(const float4*)(Bm + (size_t)(bn + row) * 512 + k0 + kc);
            *(uint2*)&Bs[row * GSTRIDE + kc] = pack4bf(w.x, w.y, w.z, w.w);
        }
        __syncthreads();
        short8 af[4], bf[4];
        #pragma unroll
        for (int mb = 0; mb < 4; ++mb)
            af[mb] = *(const short8*)&As[(wm + mb * 16 + ln) * GSTRIDE + quad * 8];
        #pragma unroll
        for (int nb = 0; nb < 4; ++nb)
            bf[nb] = *(const short8*)&Bs[(wn + nb * 16 + ln) * GSTRIDE + quad * 8];
        #pragma unroll
        for (int mb = 0; mb < 4; ++mb)
            #pragma unroll
            for (int nb = 0; nb < 4; ++nb)
                acc[mb][nb] = __builtin_amdgcn_mfma_f32_16x16x32_bf16(af[mb], bf[nb], acc[mb][nb], 0, 0, 0);
    }

    #pragma unroll
    for (int nb = 0; nb < 4; ++nb) {
        const int n = bn + wn + nb * 16 + ln;
        #pragma unroll
        for (int mb = 0; mb < 4; ++mb) {
            const int m = bm + wm + mb * 16 + quad * 4;   // global token, rows m..m+3
            if (n < 512) {
                #pragma unroll
                for (int r = 0; r < 4; ++r)
                    Qb[(size_t)(m + r) * 512 + n] = f2bf(acc[mb][nb][r] * 0.125f);
            } else if (n < 1024) {
                #pragma unroll
                for (int r = 0; r < 4; ++r)
                    Kb[(size_t)(m + r) * 512 + (n - 512)] = f2bf(acc[mb][nb][r]);
            } else {
                const int bb = m >> 10, tok = m & 1023;
                *(uint2*)(Vt + ((size_t)bb * 512 + (n - 1024)) * NN + tok) =
                    pack4bf(acc[mb][nb][0], acc[mb][nb][1], acc[mb][nb][2], acc[mb][nb][3]);
            }
        }
    }
}

// ---------------- bf16 MFMA GEMM: out = attn_out(bf16) @ out_w^T + out_b ----
__global__ __launch_bounds__(256)
void gemm_out_mfma(const unsigned short* __restrict__ Ab, const float* __restrict__ Bm,
                   const float* __restrict__ bias, float* __restrict__ C) {
    __shared__ __align__(16) unsigned short As[128 * GSTRIDE];
    __shared__ __align__(16) unsigned short Bs[128 * GSTRIDE];
    const int tid = threadIdx.x;
    const int bm = blockIdx.y * 128;
    const int bn = blockIdx.x * 128;
    const int wv = tid >> 6, lane = tid & 63, quad = lane >> 4, ln = lane & 15;
    const int wm = (wv >> 1) * 64, wn = (wv & 1) * 64;

    floatx4 acc[4][4];
    #pragma unroll
    for (int i = 0; i < 4; ++i)
        #pragma unroll
        for (int j = 0; j < 4; ++j) acc[i][j] = (floatx4){0.f, 0.f, 0.f, 0.f};

    for (int k0 = 0; k0 < 512; k0 += 32) {
        __syncthreads();
        #pragma unroll
        for (int t = 0; t < 4; ++t) {
            const int c = tid + t * 256;
            const int row = c >> 3, kc = (c & 7) * 4;
            *(uint2*)&As[row * GSTRIDE + kc] =
                *(const uint2*)(Ab + (size_t)(bm + row) * 512 + k0 + kc);
            float4 w = *(const float4*)(Bm + (size_t)(bn + row) * 512 + k0 + kc);
            *(uint2*)&Bs[row * GSTRIDE + kc] = pack4bf(w.x, w.y, w.z, w.w);
        }
        __syncthreads();
        short8 af[4], bf[4];
        #pragma unroll
        for (int mb = 0; mb < 4; ++mb)
            af[mb] = *(const short8*)&As[(wm + mb * 16 + ln) * GSTRIDE + quad * 8];
        #pragma unroll
        for (int nb = 0; nb < 4; ++nb)
            bf[nb] = *(const short8*)&Bs[(wn + nb * 16 + ln) * GSTRIDE + quad * 8];
        #pragma unroll
        for (int mb = 0; mb < 4; ++mb)
            #pragma unroll
            for (int nb = 0; nb < 4; ++nb)
                acc[mb][nb] = __builtin_amdgcn_mfma_f32_16x16x32_bf16(af[mb], bf[nb], acc[mb][nb], 0, 0, 0);
    }

    #pragma unroll
    for (int nb = 0; nb < 4; ++nb) {
        const int n = bn + wn + nb * 16 + ln;
        const float bv = bias[n];
        #pragma unroll
        for (int mb = 0; mb < 4; ++mb) {
            const int m = bm + wm + mb * 16 + quad * 4;
            #pragma unroll
            for (int r = 0; r < 4; ++r)
                C[(size_t)(m + r) * 512 + n] = acc[mb][nb][r] + bv;
        }
    }
}

// ---------------- MFMA flash attention (fixed-shift softmax) ----------------
// Block = (b, 16 queries, 8 heads); 4 waves, wave wv -> heads 2wv,2wv+1.
// MLP weights packed: w1 rows float4, w2 transposed [u][8] (alpha pre-folded).
#define BIAS_IDX(i, j, h) ((i) * 291 + (j) * 9 + (h))
__global__ __launch_bounds__(256)
void attn_kernel(const unsigned short* __restrict__ Qb,
                 const unsigned short* __restrict__ Kb,
                 const unsigned short* __restrict__ Vt,
                 const float* __restrict__ coords,
                 const unsigned char* __restrict__ mask,
                 const float* __restrict__ w1, const float* __restrict__ b1,
                 const float* __restrict__ w2, const float* __restrict__ b2,
                 const float* __restrict__ coord_scales,
                 const float* __restrict__ alpha_p,
                 unsigned short* __restrict__ attn_out) {
    const int b   = blockIdx.y;
    const int i0  = blockIdx.x * TI;
    const int tid = threadIdx.x;
    const int wv  = tid >> 6;
    const int lane = tid & 63;
    const int quad = lane >> 4;
    const int ln   = lane & 15;
    const int h0   = wv * 2;

    __shared__ float bias_s[TI * 291 + 9];              // 18.6 KB, scattered banks
    __shared__ __align__(16) unsigned short ps[NHEAD][TI][40];  // 10 KB  P bf16
    __shared__ __align__(16) float4 w1v[32];            // w1 rows
    __shared__ __align__(16) float4 w2t4[64];           // w2^T [u][8] * alpha
    __shared__ float b1s[32], b2s_[8];
    __shared__ float ci_s[TI][3];
    __shared__ float cj_s[TJ][3];
    __shared__ float mflag_s[TJ];

    const float alpha = alpha_p[0];
    if (tid < 32) w1v[tid] = *(const float4*)(w1 + tid * 4);
    if (tid < 32) b1s[tid] = b1[tid];
    {   // w2t4 flat [u*8+hh] = alpha * w2[hh*32+u]
        const int u = tid >> 3, hh = tid & 7;
        ((float*)w2t4)[tid] = alpha * w2[hh * 32 + u];
    }
    if (tid < 8)   b2s_[tid] = alpha * b2[tid];
    if (tid < TI * 3)
        ci_s[tid / 3][tid % 3] =
            coords[((size_t)b * NN + i0 + tid / 3) * 3 + tid % 3] / coord_scales[tid % 3];

    // Q A-fragments (bf16, pre-scaled by 0.125): A[m=ln][k=quad*8+jj]
    short8 qf[2][2];
    #pragma unroll
    for (int hh = 0; hh < 2; ++hh)
        #pragma unroll
        for (int kd = 0; kd < 2; ++kd)
            qf[hh][kd] = *(const short8*)(Qb + ((size_t)b * NN + i0 + ln) * 512
                                          + (h0 + hh) * 64 + kd * 32 + quad * 8);

    floatx4 oacc[2][4];
    #pragma unroll
    for (int hh = 0; hh < 2; ++hh)
        #pragma unroll
        for (int nd = 0; nd < 4; ++nd)
            oacc[hh][nd] = (floatx4){0.f, 0.f, 0.f, 0.f};
    float l_part[2][4];
    #pragma unroll
    for (int hh = 0; hh < 2; ++hh)
        #pragma unroll
        for (int r = 0; r < 4; ++r) l_part[hh][r] = 0.f;

    const int mi = tid >> 4;       // MLP: thread's query index (0..15)
    const int mj = tid & 15;       // MLP: thread's j base

    for (int jt = 0; jt < NN / TJ; ++jt) {
        const int j0 = jt * TJ;
        if (tid < TJ * 3)
            cj_s[tid / 3][tid % 3] =
                coords[((size_t)b * NN + j0 + tid / 3) * 3 + tid % 3] / coord_scales[tid % 3];
        if (tid < TJ) mflag_s[tid] = mask[(size_t)b * NN + j0 + tid] ? 1.0f : 0.0f;
        __syncthreads();   // barrier C: cj_s/mflag_s ready

        // ---- MLP: 2 pairs per thread (bias includes alpha) ----
        #pragma unroll
        for (int kk = 0; kk < 2; ++kk) {
            const int j = mj + 16 * kk;
            float acc[8];
            if (i0 + mi < NS || j0 + j < NS) {
                #pragma unroll
                for (int hh = 0; hh < 8; ++hh) acc[hh] = 0.0f;
            } else {
                const float dx = ci_s[mi][0] - cj_s[j][0];
                const float dy = ci_s[mi][1] - cj_s[j][1];
                const float dz = ci_s[mi][2] - cj_s[j][2];
                const float dist = sqrtf(dx * dx + dy * dy + dz * dz);
                #pragma unroll
                for (int hh = 0; hh < 8; ++hh) acc[hh] = b2s_[hh];
                #pragma unroll 8
                for (int u = 0; u < 32; ++u) {
                    const float4 wa = w1v[u];
                    float hu = fmaf(wa.x, dx, fmaf(wa.y, dy,
                               fmaf(wa.z, dz, fmaf(wa.w, dist, b1s[u]))));
                    hu = gelu_fast(hu);
                    const float4 wb0 = w2t4[u * 2];
                    const float4 wb1 = w2t4[u * 2 + 1];
                    acc[0] = fmaf(hu, wb0.x, acc[0]); acc[1] = fmaf(hu, wb0.y, acc[1]);
                    acc[2] = fmaf(hu, wb0.z, acc[2]); acc[3] = fmaf(hu, wb0.w, acc[3]);
                    acc[4] = fmaf(hu, wb1.x, acc[4]); acc[5] = fmaf(hu, wb1.y, acc[5]);
                    acc[6] = fmaf(hu, wb1.z, acc[6]); acc[7] = fmaf(hu, wb1.w, acc[7]);
                }
            }
            #pragma unroll
            for (int hh = 0; hh < 8; ++hh) bias_s[BIAS_IDX(mi, j, hh)] = acc[hh];
        }
        __syncthreads();   // barrier A: bias_s ready

        // ---- QK mfma + bias + exp(v - FIX_M) -> P (LDS, bf16) ----
        const float mf0 = mflag_s[ln], mf1 = mflag_s[16 + ln];
        #pragma unroll
        for (int hh = 0; hh < 2; ++hh) {
            const int h = h0 + hh;
            const unsigned short* kbase = Kb + ((size_t)b * NN + j0) * 512 + h * 64;
            short8 k00 = *(const short8*)(kbase + (size_t)ln * 512 + quad * 8);
            short8 k01 = *(const short8*)(kbase + (size_t)ln * 512 + 32 + quad * 8);
            short8 k10 = *(const short8*)(kbase + (size_t)(16 + ln) * 512 + quad * 8);
            short8 k11 = *(const short8*)(kbase + (size_t)(16 + ln) * 512 + 32 + quad * 8);
            floatx4 s0 = (floatx4){0.f, 0.f, 0.f, 0.f};
            floatx4 s1 = (floatx4){0.f, 0.f, 0.f, 0.f};
            s0 = __builtin_amdgcn_mfma_f32_16x16x32_bf16(qf[hh][0], k00, s0, 0, 0, 0);
            s0 = __builtin_amdgcn_mfma_f32_16x16x32_bf16(qf[hh][1], k01, s0, 0, 0, 0);
            s1 = __builtin_amdgcn_mfma_f32_16x16x32_bf16(qf[hh][0], k10, s1, 0, 0, 0);
            s1 = __builtin_amdgcn_mfma_f32_16x16x32_bf16(qf[hh][1], k11, s1, 0, 0, 0);
            #pragma unroll
            for (int r = 0; r < 4; ++r) {
                const int row = quad * 4 + r;
                float v0 = s0[r] + bias_s[BIAS_IDX(row, ln, h)];
                float v1 = s1[r] + bias_s[BIAS_IDX(row, 16 + ln, h)];
                v0 = (mf0 != 0.0f) ? -1e30f : v0;
                v1 = (mf1 != 0.0f) ? -1e30f : v1;
                const float e0 = __expf(v0 - FIX_M);
                const float e1 = __expf(v1 - FIX_M);
                l_part[hh][r] += e0 + e1;
                ps[h][row][ln]      = f2bf(e0);
                ps[h][row][16 + ln] = f2bf(e1);
            }
        }
        __syncthreads();   // barrier B: tile consumed, P ready

        // ---- PV mfma: A = P (LDS), B = Vt fragments (global) ----
        #pragma unroll
        for (int hh = 0; hh < 2; ++hh) {
            const int h = h0 + hh;
            short8 pa = *(const short8*)&ps[h][ln][quad * 8];
            const unsigned short* vbase = Vt + ((size_t)b * 512 + h * 64) * NN + j0 + quad * 8;
            #pragma unroll
            for (int nd = 0; nd < 4; ++nd) {
                short8 vf = *(const short8*)(vbase + (size_t)(nd * 16 + ln) * NN);
                oacc[hh][nd] = __builtin_amdgcn_mfma_f32_16x16x32_bf16(pa, vf, oacc[hh][nd], 0, 0, 0);
            }
        }
    }

    // epilogue: reduce l over 16 lanes per row, O /= l, store bf16
    #pragma unroll
    for (int hh = 0; hh < 2; ++hh) {
        float rl[4];
        #pragma unroll
        for (int r = 0; r < 4; ++r) {
            float l = l_part[hh][r];
            l += __shfl_xor(l, 1, 64);
            l += __shfl_xor(l, 2, 64);
            l += __shfl_xor(l, 4, 64);
            l += __shfl_xor(l, 8, 64);
            rl[r] = 1.0f / l;
        }
        #pragma unroll
        for (int nd = 0; nd < 4; ++nd)
            #pragma unroll
            for (int r = 0; r < 4; ++r)
                attn_out[((size_t)b * NN + i0 + quad * 4 + r) * 512
                         + (h0 + hh) * 64 + nd * 16 + ln] = f2bf(oacc[hh][nd][r] * rl[r]);
    }
}

extern "C" void kernel_launch(void* const* d_in, const int* in_sizes, int n_in,
                              void* d_out, int out_size, void* d_ws, size_t ws_size,
                              hipStream_t stream) {
    const float* x        = (const float*)d_in[0];
    const float* coords   = (const float*)d_in[1];
    const unsigned char* kpm = (const unsigned char*)d_in[2];
    const float* qkv_w    = (const float*)d_in[3];
    const float* out_w    = (const float*)d_in[4];
    const float* out_b    = (const float*)d_in[5];
    const float* alpha    = (const float*)d_in[6];
    const float* w1       = (const float*)d_in[7];
    const float* b1       = (const float*)d_in[8];
    const float* w2       = (const float*)d_in[9];
    const float* b2       = (const float*)d_in[10];
    const float* cscales  = (const float*)d_in[11];
    float* out = (float*)d_out;

    const int M = BB * NN;
    // workspace: Qb/Kb/Vt/attn_out all bf16 = 4 x 8.39 MB = 33.6 MB
    unsigned short* Qb = (unsigned short*)d_ws;
    unsigned short* Kb = Qb + (size_t)M * D_MODEL;
    unsigned short* Vt = Kb + (size_t)M * D_MODEL;
    unsigned short* Ao = Vt + (size_t)M * D_MODEL;

    {
        dim3 grid(3 * D_MODEL / 128, M / 128);   // 12 x 64
        gemm_qkv_mfma<<<grid, 256, 0, stream>>>(x, qkv_w, Qb, Kb, Vt);
    }
    {
        dim3 grid(NN / TI, BB);
        attn_kernel<<<grid, 256, 0, stream>>>(Qb, Kb, Vt, coords, kpm, w1, b1, w2, b2,
                                              cscales, alpha, Ao);
    }
    {
        dim3 grid(D_MODEL / 128, M / 128);       // 4 x 64
        gemm_out_mfma<<<grid, 256, 0, stream>>>(Ao, out_w, out_b, out);
    }
}

// Round 8
// 497.329 us; speedup vs baseline: 11.9947x; 1.0144x over previous
//
#include <hip/hip_runtime.h>
#include <math.h>

#define D_MODEL 512
#define NHEAD   8
#define HEAD_DIM 64
#define BB      8
#define NN      1024
#define NS      1
#define TI      16
#define TJ      32
#define NT      (NN / TJ)
#define FIX_M   10.0f
#define GSTRIDE 40   // LDS row stride (shorts) for MFMA gemm tiles

typedef __attribute__((ext_vector_type(8))) short short8;
typedef __attribute__((ext_vector_type(4))) float floatx4;

// Branch-free gelu: erf via Abramowitz-Stegun 7.1.26 (|err| <= 1.5e-7).
__device__ __forceinline__ float gelu_fast(float x) {
    const float s = x * 0.70710678118654752f;
    const float u = fabsf(s);
    const float t = __builtin_amdgcn_rcpf(fmaf(0.3275911f, u, 1.0f));
    float p = fmaf(1.061405429f, t, -1.453152027f);
    p = fmaf(p, t, 1.421413741f);
    p = fmaf(p, t, -0.284496736f);
    p = fmaf(p, t, 0.254829592f);
    p = p * t;
    const float e = __expf(-u * u);
    float erf_u = fmaf(-p, e, 1.0f);
    erf_u = copysignf(erf_u, s);
    return 0.5f * x * (1.0f + erf_u);
}

__device__ __forceinline__ unsigned short f2bf(float f) {
    unsigned u = __float_as_uint(f);
    u = (u + 0x7fffu + ((u >> 16) & 1u)) >> 16;   // RNE
    return (unsigned short)u;
}

__device__ __forceinline__ uint2 pack4bf(float a, float b, float c, float d) {
    uint2 p;
    p.x = (unsigned)f2bf(a) | ((unsigned)f2bf(b) << 16);
    p.y = (unsigned)f2bf(c) | ((unsigned)f2bf(d) << 16);
    return p;
}

// ---------------- bf16 MFMA GEMM: qkv = x @ qkv_w^T, fused bf16 epilogue ----
__global__ __launch_bounds__(256)
void gemm_qkv_mfma(const float* __restrict__ A, const float* __restrict__ Bm,
                   unsigned short* __restrict__ Qb, unsigned short* __restrict__ Kb,
                   unsigned short* __restrict__ Vt) {
    __shared__ __align__(16) unsigned short As[128 * GSTRIDE];
    __shared__ __align__(16) unsigned short Bs[128 * GSTRIDE];
    const int tid = threadIdx.x;
    const int bm = blockIdx.y * 128;
    const int bn = blockIdx.x * 128;
    const int wv = tid >> 6, lane = tid & 63, quad = lane >> 4, ln = lane & 15;
    const int wm = (wv >> 1) * 64, wn = (wv & 1) * 64;

    floatx4 acc[4][4];
    #pragma unroll
    for (int i = 0; i < 4; ++i)
        #pragma unroll
        for (int j = 0; j < 4; ++j) acc[i][j] = (floatx4){0.f, 0.f, 0.f, 0.f};

    for (int k0 = 0; k0 < 512; k0 += 32) {
        __syncthreads();
        #pragma unroll
        for (int t = 0; t < 4; ++t) {
            const int c = tid + t * 256;
            const int row = c >> 3, kc = (c & 7) * 4;
            float4 v = *(const float4*)(A + (size_t)(bm + row) * 512 + k0 + kc);
            *(uint2*)&As[row * GSTRIDE + kc] = pack4bf(v.x, v.y, v.z, v.w);
            float4 w = *(const float4*)(Bm + (size_t)(bn + row) * 512 + k0 + kc);
            *(uint2*)&Bs[row * GSTRIDE + kc] = pack4bf(w.x, w.y, w.z, w.w);
        }
        __syncthreads();
        short8 af[4], bf[4];
        #pragma unroll
        for (int mb = 0; mb < 4; ++mb)
            af[mb] = *(const short8*)&As[(wm + mb * 16 + ln) * GSTRIDE + quad * 8];
        #pragma unroll
        for (int nb = 0; nb < 4; ++nb)
            bf[nb] = *(const short8*)&Bs[(wn + nb * 16 + ln) * GSTRIDE + quad * 8];
        #pragma unroll
        for (int mb = 0; mb < 4; ++mb)
            #pragma unroll
            for (int nb = 0; nb < 4; ++nb)
                acc[mb][nb] = __builtin_amdgcn_mfma_f32_16x16x32_bf16(af[mb], bf[nb], acc[mb][nb], 0, 0, 0);
    }

    #pragma unroll
    for (int nb = 0; nb < 4; ++nb) {
        const int n = bn + wn + nb * 16 + ln;
        #pragma unroll
        for (int mb = 0; mb < 4; ++mb) {
            const int m = bm + wm + mb * 16 + quad * 4;
            if (n < 512) {
                #pragma unroll
                for (int r = 0; r < 4; ++r)
                    Qb[(size_t)(m + r) * 512 + n] = f2bf(acc[mb][nb][r] * 0.125f);
            } else if (n < 1024) {
                #pragma unroll
                for (int r = 0; r < 4; ++r)
                    Kb[(size_t)(m + r) * 512 + (n - 512)] = f2bf(acc[mb][nb][r]);
            } else {
                const int bb = m >> 10, tok = m & 1023;
                *(uint2*)(Vt + ((size_t)bb * 512 + (n - 1024)) * NN + tok) =
                    pack4bf(acc[mb][nb][0], acc[mb][nb][1], acc[mb][nb][2], acc[mb][nb][3]);
            }
        }
    }
}

// ---------------- bf16 MFMA GEMM: out = attn_out(bf16) @ out_w^T + out_b ----
__global__ __launch_bounds__(256)
void gemm_out_mfma(const unsigned short* __restrict__ Ab, const float* __restrict__ Bm,
                   const float* __restrict__ bias, float* __restrict__ C) {
    __shared__ __align__(16) unsigned short As[128 * GSTRIDE];
    __shared__ __align__(16) unsigned short Bs[128 * GSTRIDE];
    const int tid = threadIdx.x;
    const int bm = blockIdx.y * 128;
    const int bn = blockIdx.x * 128;
    const int wv = tid >> 6, lane = tid & 63, quad = lane >> 4, ln = lane & 15;
    const int wm = (wv >> 1) * 64, wn = (wv & 1) * 64;

    floatx4 acc[4][4];
    #pragma unroll
    for (int i = 0; i < 4; ++i)
        #pragma unroll
        for (int j = 0; j < 4; ++j) acc[i][j] = (floatx4){0.f, 0.f, 0.f, 0.f};

    for (int k0 = 0; k0 < 512; k0 += 32) {
        __syncthreads();
        #pragma unroll
        for (int t = 0; t < 4; ++t) {
            const int c = tid + t * 256;
            const int row = c >> 3, kc = (c & 7) * 4;
            *(uint2*)&As[row * GSTRIDE + kc] =
                *(const uint2*)(Ab + (size_t)(bm + row) * 512 + k0 + kc);
            float4 w = *(const float4*)(Bm + (size_t)(bn + row) * 512 + k0 + kc);
            *(uint2*)&Bs[row * GSTRIDE + kc] = pack4bf(w.x, w.y, w.z, w.w);
        }
        __syncthreads();
        short8 af[4], bf[4];
        #pragma unroll
        for (int mb = 0; mb < 4; ++mb)
            af[mb] = *(const short8*)&As[(wm + mb * 16 + ln) * GSTRIDE + quad * 8];
        #pragma unroll
        for (int nb = 0; nb < 4; ++nb)
            bf[nb] = *(const short8*)&Bs[(wn + nb * 16 + ln) * GSTRIDE + quad * 8];
        #pragma unroll
        for (int mb = 0; mb < 4; ++mb)
            #pragma unroll
            for (int nb = 0; nb < 4; ++nb)
                acc[mb][nb] = __builtin_amdgcn_mfma_f32_16x16x32_bf16(af[mb], bf[nb], acc[mb][nb], 0, 0, 0);
    }

    #pragma unroll
    for (int nb = 0; nb < 4; ++nb) {
        const int n = bn + wn + nb * 16 + ln;
        const float bv = bias[n];
        #pragma unroll
        for (int mb = 0; mb < 4; ++mb) {
            const int m = bm + wm + mb * 16 + quad * 4;
            #pragma unroll
            for (int r = 0; r < 4; ++r)
                C[(size_t)(m + r) * 512 + n] = acc[mb][nb][r] + bv;
        }
    }
}

// ---------------- MFMA flash attention, software-pipelined ----------------
// Block = (b, 16 queries, 8 heads); 4 waves, wave wv -> heads 2wv,2wv+1.
// ONE barrier per j-tile: region = { K/V loads(jt) ; MLP(jt+1) ; QK(jt) ; PV(jt) ;
// stage(jt+2) }. bias_s double-buffered (MLP->QK is the only cross-wave dep);
// ps (P round-trip) is within-wave, needs no barrier. coords/mask quad-buffered.
#define BIAS_IDX(i, j, h) ((i) * 291 + (j) * 9 + (h))
__global__ __launch_bounds__(256)
void attn_kernel(const unsigned short* __restrict__ Qb,
                 const unsigned short* __restrict__ Kb,
                 const unsigned short* __restrict__ Vt,
                 const float* __restrict__ coords,
                 const unsigned char* __restrict__ mask,
                 const float* __restrict__ w1, const float* __restrict__ b1,
                 const float* __restrict__ w2, const float* __restrict__ b2,
                 const float* __restrict__ coord_scales,
                 const float* __restrict__ alpha_p,
                 unsigned short* __restrict__ attn_out) {
    const int b   = blockIdx.y;
    const int i0  = blockIdx.x * TI;
    const int tid = threadIdx.x;
    const int wv  = tid >> 6;
    const int lane = tid & 63;
    const int quad = lane >> 4;
    const int ln   = lane & 15;
    const int h0   = wv * 2;

    __shared__ float bias_s[2][TI * 291 + 9];                   // 2 x 18.6 KB
    __shared__ __align__(16) unsigned short ps[NHEAD][TI][40];  // 10 KB
    __shared__ __align__(16) float4 w1v[32];
    __shared__ __align__(16) float4 w2t4[64];
    __shared__ float b1s[32], b2s_[8];
    __shared__ float ci_s[TI][3];
    __shared__ float cj_s[4][TJ][3];
    __shared__ float mflag_s[4][TJ];

    const float alpha = alpha_p[0];
    if (tid < 32) w1v[tid] = *(const float4*)(w1 + tid * 4);
    if (tid < 32) b1s[tid] = b1[tid];
    {   // w2t4 flat [u*8+hh] = alpha * w2[hh*32+u]
        const int u = tid >> 3, hh = tid & 7;
        ((float*)w2t4)[tid] = alpha * w2[hh * 32 + u];
    }
    if (tid < 8)   b2s_[tid] = alpha * b2[tid];
    if (tid < TI * 3)
        ci_s[tid / 3][tid % 3] =
            coords[((size_t)b * NN + i0 + tid / 3) * 3 + tid % 3] / coord_scales[tid % 3];

    // Q A-fragments (bf16, pre-scaled by 0.125)
    short8 qf[2][2];
    #pragma unroll
    for (int hh = 0; hh < 2; ++hh)
        #pragma unroll
        for (int kd = 0; kd < 2; ++kd)
            qf[hh][kd] = *(const short8*)(Qb + ((size_t)b * NN + i0 + ln) * 512
                                          + (h0 + hh) * 64 + kd * 32 + quad * 8);

    floatx4 oacc[2][4];
    #pragma unroll
    for (int hh = 0; hh < 2; ++hh)
        #pragma unroll
        for (int nd = 0; nd < 4; ++nd)
            oacc[hh][nd] = (floatx4){0.f, 0.f, 0.f, 0.f};
    float l_part[2][4];
    #pragma unroll
    for (int hh = 0; hh < 2; ++hh)
        #pragma unroll
        for (int r = 0; r < 4; ++r) l_part[hh][r] = 0.f;

    const int mi = tid >> 4;
    const int mj = tid & 15;

    // ---- staging helper (tiles: coords scaled + mask flags) ----
    #define STAGE(s_) do { const int ss = (s_);                                     \
        if (ss < NT) {                                                              \
            if (tid < TJ * 3)                                                       \
                cj_s[ss & 3][tid / 3][tid % 3] =                                    \
                    coords[((size_t)b * NN + ss * TJ + tid / 3) * 3 + tid % 3]      \
                    / coord_scales[tid % 3];                                        \
            if (tid < TJ)                                                           \
                mflag_s[ss & 3][tid] =                                              \
                    mask[(size_t)b * NN + ss * TJ + tid] ? 1.0f : 0.0f;             \
        } } while (0)

    // ---- MLP helper: this thread's 2 pairs of tile t -> bias_s[t&1] ----
    #define MLP(t_) do { const int tt = (t_);                                       \
        if (tt < NT) {                                                              \
            const int j0m = tt * TJ;                                                \
            float* bout = bias_s[tt & 1];                                           \
            const float (*cj)[3] = cj_s[tt & 3];                                    \
            _Pragma("unroll")                                                       \
            for (int kk = 0; kk < 2; ++kk) {                                        \
                const int j = mj + 16 * kk;                                         \
                float acc[8];                                                       \
                if (i0 + mi < NS || j0m + j < NS) {                                 \
                    _Pragma("unroll")                                               \
                    for (int hh = 0; hh < 8; ++hh) acc[hh] = 0.0f;                  \
                } else {                                                            \
                    const float dx = ci_s[mi][0] - cj[j][0];                        \
                    const float dy = ci_s[mi][1] - cj[j][1];                        \
                    const float dz = ci_s[mi][2] - cj[j][2];                        \
                    const float dist = sqrtf(dx * dx + dy * dy + dz * dz);          \
                    _Pragma("unroll")                                               \
                    for (int hh = 0; hh < 8; ++hh) acc[hh] = b2s_[hh];              \
                    _Pragma("unroll 8")                                             \
                    for (int u = 0; u < 32; ++u) {                                  \
                        const float4 wa = w1v[u];                                   \
                        float hu = fmaf(wa.x, dx, fmaf(wa.y, dy,                    \
                                   fmaf(wa.z, dz, fmaf(wa.w, dist, b1s[u]))));      \
                        hu = gelu_fast(hu);                                         \
                        const float4 wb0 = w2t4[u * 2];                             \
                        const float4 wb1 = w2t4[u * 2 + 1];                         \
                        acc[0] = fmaf(hu, wb0.x, acc[0]);                           \
                        acc[1] = fmaf(hu, wb0.y, acc[1]);                           \
                        acc[2] = fmaf(hu, wb0.z, acc[2]);                           \
                        acc[3] = fmaf(hu, wb0.w, acc[3]);                           \
                        acc[4] = fmaf(hu, wb1.x, acc[4]);                           \
                        acc[5] = fmaf(hu, wb1.y, acc[5]);                           \
                        acc[6] = fmaf(hu, wb1.z, acc[6]);                           \
                        acc[7] = fmaf(hu, wb1.w, acc[7]);                           \
                    }                                                               \
                }                                                                   \
                _Pragma("unroll")                                                   \
                for (int hh = 0; hh < 8; ++hh) bout[BIAS_IDX(mi, j, hh)] = acc[hh]; \
            }                                                                       \
        } } while (0)

    // ---- prologue: stage(0); MLP(0); stage(1) ----
    STAGE(0);
    __syncthreads();
    MLP(0);
    STAGE(1);
    __syncthreads();

    for (int jt = 0; jt < NT; ++jt) {
        const int j0 = jt * TJ;
        const int pb = jt & 1;
        const int ps_slot = jt & 3;

        // ---- issue K and V global loads for tile jt (fly under MLP) ----
        short8 kf[2][4], vf[2][4];
        #pragma unroll
        for (int hh = 0; hh < 2; ++hh) {
            const unsigned short* kbase = Kb + ((size_t)b * NN + j0) * 512 + (h0 + hh) * 64;
            kf[hh][0] = *(const short8*)(kbase + (size_t)ln * 512 + quad * 8);
            kf[hh][1] = *(const short8*)(kbase + (size_t)ln * 512 + 32 + quad * 8);
            kf[hh][2] = *(const short8*)(kbase + (size_t)(16 + ln) * 512 + quad * 8);
            kf[hh][3] = *(const short8*)(kbase + (size_t)(16 + ln) * 512 + 32 + quad * 8);
            const unsigned short* vbase = Vt + ((size_t)b * 512 + (h0 + hh) * 64) * NN + j0 + quad * 8;
            #pragma unroll
            for (int nd = 0; nd < 4; ++nd)
                vf[hh][nd] = *(const short8*)(vbase + (size_t)(nd * 16 + ln) * NN);
        }

        // ---- stage tile jt+2 (writes slot (jt+2)&3; readers use jt&3,(jt+1)&3) --
        STAGE(jt + 2);

        // ---- MLP for tile jt+1 -> bias_s[(jt+1)&1] (VALU; overlaps loads) ----
        MLP(jt + 1);

        // ---- QK mfma + bias + exp -> ps (reads bias_s[jt&1], within-wave ps) ----
        const float mf0 = mflag_s[ps_slot][ln], mf1 = mflag_s[ps_slot][16 + ln];
        #pragma unroll
        for (int hh = 0; hh < 2; ++hh) {
            const int h = h0 + hh;
            floatx4 s0 = (floatx4){0.f, 0.f, 0.f, 0.f};
            floatx4 s1 = (floatx4){0.f, 0.f, 0.f, 0.f};
            s0 = __builtin_amdgcn_mfma_f32_16x16x32_bf16(qf[hh][0], kf[hh][0], s0, 0, 0, 0);
            s0 = __builtin_amdgcn_mfma_f32_16x16x32_bf16(qf[hh][1], kf[hh][1], s0, 0, 0, 0);
            s1 = __builtin_amdgcn_mfma_f32_16x16x32_bf16(qf[hh][0], kf[hh][2], s1, 0, 0, 0);
            s1 = __builtin_amdgcn_mfma_f32_16x16x32_bf16(qf[hh][1], kf[hh][3], s1, 0, 0, 0);
            #pragma unroll
            for (int r = 0; r < 4; ++r) {
                const int row = quad * 4 + r;
                float v0 = s0[r] + bias_s[pb][BIAS_IDX(row, ln, h)];
                float v1 = s1[r] + bias_s[pb][BIAS_IDX(row, 16 + ln, h)];
                v0 = (mf0 != 0.0f) ? -1e30f : v0;
                v1 = (mf1 != 0.0f) ? -1e30f : v1;
                const float e0 = __expf(v0 - FIX_M);
                const float e1 = __expf(v1 - FIX_M);
                l_part[hh][r] += e0 + e1;
                ps[h][row][ln]      = f2bf(e0);
                ps[h][row][16 + ln] = f2bf(e1);
            }
        }

        // ---- PV mfma (ps read is within-wave; compiler orders via lgkmcnt) ----
        #pragma unroll
        for (int hh = 0; hh < 2; ++hh) {
            const int h = h0 + hh;
            short8 pa = *(const short8*)&ps[h][ln][quad * 8];
            #pragma unroll
            for (int nd = 0; nd < 4; ++nd)
                oacc[hh][nd] = __builtin_amdgcn_mfma_f32_16x16x32_bf16(pa, vf[hh][nd], oacc[hh][nd], 0, 0, 0);
        }

        __syncthreads();   // single barrier: bias_s[(jt+1)&1] ready; slots rotate
    }

    // epilogue: reduce l over 16 lanes per row, O /= l, store bf16
    #pragma unroll
    for (int hh = 0; hh < 2; ++hh) {
        float rl[4];
        #pragma unroll
        for (int r = 0; r < 4; ++r) {
            float l = l_part[hh][r];
            l += __shfl_xor(l, 1, 64);
            l += __shfl_xor(l, 2, 64);
            l += __shfl_xor(l, 4, 64);
            l += __shfl_xor(l, 8, 64);
            rl[r] = 1.0f / l;
        }
        #pragma unroll
        for (int nd = 0; nd < 4; ++nd)
            #pragma unroll
            for (int r = 0; r < 4; ++r)
                attn_out[((size_t)b * NN + i0 + quad * 4 + r) * 512
                         + (h0 + hh) * 64 + nd * 16 + ln] = f2bf(oacc[hh][nd][r] * rl[r]);
    }
    #undef STAGE
    #undef MLP
}

extern "C" void kernel_launch(void* const* d_in, const int* in_sizes, int n_in,
                              void* d_out, int out_size, void* d_ws, size_t ws_size,
                              hipStream_t stream) {
    const float* x        = (const float*)d_in[0];
    const float* coords   = (const float*)d_in[1];
    const unsigned char* kpm = (const unsigned char*)d_in[2];
    const float* qkv_w    = (const float*)d_in[3];
    const float* out_w    = (const float*)d_in[4];
    const float* out_b    = (const float*)d_in[5];
    const float* alpha    = (const float*)d_in[6];
    const float* w1       = (const float*)d_in[7];
    const float* b1       = (const float*)d_in[8];
    const float* w2       = (const float*)d_in[9];
    const float* b2       = (const float*)d_in[10];
    const float* cscales  = (const float*)d_in[11];
    float* out = (float*)d_out;

    const int M = BB * NN;
    unsigned short* Qb = (unsigned short*)d_ws;
    unsigned short* Kb = Qb + (size_t)M * D_MODEL;
    unsigned short* Vt = Kb + (size_t)M * D_MODEL;
    unsigned short* Ao = Vt + (size_t)M * D_MODEL;

    {
        dim3 grid(3 * D_MODEL / 128, M / 128);
        gemm_qkv_mfma<<<grid, 256, 0, stream>>>(x, qkv_w, Qb, Kb, Vt);
    }
    {
        dim3 grid(NN / TI, BB);
        attn_kernel<<<grid, 256, 0, stream>>>(Qb, Kb, Vt, coords, kpm, w1, b1, w2, b2,
                                              cscales, alpha, Ao);
    }
    {
        dim3 grid(D_MODEL / 128, M / 128);
        gemm_out_mfma<<<grid, 256, 0, stream>>>(Ao, out_w, out_b, out);
    }
}

// Round 9
// 422.279 us; speedup vs baseline: 14.1265x; 1.1777x over previous
//
#include <hip/hip_runtime.h>
#include <math.h>

#define D_MODEL 512
#define NHEAD   8
#define HEAD_DIM 64
#define BB      8
#define NN      1024
#define NS      1
#define TI      16
#define TJ      32
#define NT      (NN / TJ)
#define FIX_M   10.0f
#define GSTRIDE 40   // LDS row stride (shorts) for MFMA gemm tiles

typedef __attribute__((ext_vector_type(8))) short short8;
typedef __attribute__((ext_vector_type(4))) float floatx4;

// Branch-free gelu: erf via Abramowitz-Stegun 7.1.26 (|err| <= 1.5e-7).
__device__ __forceinline__ float gelu_fast(float x) {
    const float s = x * 0.70710678118654752f;
    const float u = fabsf(s);
    const float t = __builtin_amdgcn_rcpf(fmaf(0.3275911f, u, 1.0f));
    float p = fmaf(1.061405429f, t, -1.453152027f);
    p = fmaf(p, t, 1.421413741f);
    p = fmaf(p, t, -0.284496736f);
    p = fmaf(p, t, 0.254829592f);
    p = p * t;
    const float e = __expf(-u * u);
    float erf_u = fmaf(-p, e, 1.0f);
    erf_u = copysignf(erf_u, s);
    return 0.5f * x * (1.0f + erf_u);
}

__device__ __forceinline__ unsigned short f2bf(float f) {
    unsigned u = __float_as_uint(f);
    u = (u + 0x7fffu + ((u >> 16) & 1u)) >> 16;   // RNE
    return (unsigned short)u;
}

__device__ __forceinline__ uint2 pack4bf(float a, float b, float c, float d) {
    uint2 p;
    p.x = (unsigned)f2bf(a) | ((unsigned)f2bf(b) << 16);
    p.y = (unsigned)f2bf(c) | ((unsigned)f2bf(d) << 16);
    return p;
}

// ---------------- bf16 MFMA GEMM: qkv = x @ qkv_w^T, fused bf16 epilogue ----
__global__ __launch_bounds__(256)
void gemm_qkv_mfma(const float* __restrict__ A, const float* __restrict__ Bm,
                   unsigned short* __restrict__ Qb, unsigned short* __restrict__ Kb,
                   unsigned short* __restrict__ Vt) {
    __shared__ __align__(16) unsigned short As[128 * GSTRIDE];
    __shared__ __align__(16) unsigned short Bs[128 * GSTRIDE];
    const int tid = threadIdx.x;
    const int bm = blockIdx.y * 128;
    const int bn = blockIdx.x * 128;
    const int wv = tid >> 6, lane = tid & 63, quad = lane >> 4, ln = lane & 15;
    const int wm = (wv >> 1) * 64, wn = (wv & 1) * 64;

    floatx4 acc[4][4];
    #pragma unroll
    for (int i = 0; i < 4; ++i)
        #pragma unroll
        for (int j = 0; j < 4; ++j) acc[i][j] = (floatx4){0.f, 0.f, 0.f, 0.f};

    for (int k0 = 0; k0 < 512; k0 += 32) {
        __syncthreads();
        #pragma unroll
        for (int t = 0; t < 4; ++t) {
            const int c = tid + t * 256;
            const int row = c >> 3, kc = (c & 7) * 4;
            float4 v = *(const float4*)(A + (size_t)(bm + row) * 512 + k0 + kc);
            *(uint2*)&As[row * GSTRIDE + kc] = pack4bf(v.x, v.y, v.z, v.w);
            float4 w = *(const float4*)(Bm + (size_t)(bn + row) * 512 + k0 + kc);
            *(uint2*)&Bs[row * GSTRIDE + kc] = pack4bf(w.x, w.y, w.z, w.w);
        }
        __syncthreads();
        short8 af[4], bf[4];
        #pragma unroll
        for (int mb = 0; mb < 4; ++mb)
            af[mb] = *(const short8*)&As[(wm + mb * 16 + ln) * GSTRIDE + quad * 8];
        #pragma unroll
        for (int nb = 0; nb < 4; ++nb)
            bf[nb] = *(const short8*)&Bs[(wn + nb * 16 + ln) * GSTRIDE + quad * 8];
        #pragma unroll
        for (int mb = 0; mb < 4; ++mb)
            #pragma unroll
            for (int nb = 0; nb < 4; ++nb)
                acc[mb][nb] = __builtin_amdgcn_mfma_f32_16x16x32_bf16(af[mb], bf[nb], acc[mb][nb], 0, 0, 0);
    }

    #pragma unroll
    for (int nb = 0; nb < 4; ++nb) {
        const int n = bn + wn + nb * 16 + ln;
        #pragma unroll
        for (int mb = 0; mb < 4; ++mb) {
            const int m = bm + wm + mb * 16 + quad * 4;
            if (n < 512) {
                #pragma unroll
                for (int r = 0; r < 4; ++r)
                    Qb[(size_t)(m + r) * 512 + n] = f2bf(acc[mb][nb][r] * 0.125f);
            } else if (n < 1024) {
                #pragma unroll
                for (int r = 0; r < 4; ++r)
                    Kb[(size_t)(m + r) * 512 + (n - 512)] = f2bf(acc[mb][nb][r]);
            } else {
                const int bb = m >> 10, tok = m & 1023;
                *(uint2*)(Vt + ((size_t)bb * 512 + (n - 1024)) * NN + tok) =
                    pack4bf(acc[mb][nb][0], acc[mb][nb][1], acc[mb][nb][2], acc[mb][nb][3]);
            }
        }
    }
}

// ---------------- bf16 MFMA GEMM: out = attn_out(bf16) @ out_w^T + out_b ----
__global__ __launch_bounds__(256)
void gemm_out_mfma(const unsigned short* __restrict__ Ab, const float* __restrict__ Bm,
                   const float* __restrict__ bias, float* __restrict__ C) {
    __shared__ __align__(16) unsigned short As[128 * GSTRIDE];
    __shared__ __align__(16) unsigned short Bs[128 * GSTRIDE];
    const int tid = threadIdx.x;
    const int bm = blockIdx.y * 128;
    const int bn = blockIdx.x * 128;
    const int wv = tid >> 6, lane = tid & 63, quad = lane >> 4, ln = lane & 15;
    const int wm = (wv >> 1) * 64, wn = (wv & 1) * 64;

    floatx4 acc[4][4];
    #pragma unroll
    for (int i = 0; i < 4; ++i)
        #pragma unroll
        for (int j = 0; j < 4; ++j) acc[i][j] = (floatx4){0.f, 0.f, 0.f, 0.f};

    for (int k0 = 0; k0 < 512; k0 += 32) {
        __syncthreads();
        #pragma unroll
        for (int t = 0; t < 4; ++t) {
            const int c = tid + t * 256;
            const int row = c >> 3, kc = (c & 7) * 4;
            *(uint2*)&As[row * GSTRIDE + kc] =
                *(const uint2*)(Ab + (size_t)(bm + row) * 512 + k0 + kc);
            float4 w = *(const float4*)(Bm + (size_t)(bn + row) * 512 + k0 + kc);
            *(uint2*)&Bs[row * GSTRIDE + kc] = pack4bf(w.x, w.y, w.z, w.w);
        }
        __syncthreads();
        short8 af[4], bf[4];
        #pragma unroll
        for (int mb = 0; mb < 4; ++mb)
            af[mb] = *(const short8*)&As[(wm + mb * 16 + ln) * GSTRIDE + quad * 8];
        #pragma unroll
        for (int nb = 0; nb < 4; ++nb)
            bf[nb] = *(const short8*)&Bs[(wn + nb * 16 + ln) * GSTRIDE + quad * 8];
        #pragma unroll
        for (int mb = 0; mb < 4; ++mb)
            #pragma unroll
            for (int nb = 0; nb < 4; ++nb)
                acc[mb][nb] = __builtin_amdgcn_mfma_f32_16x16x32_bf16(af[mb], bf[nb], acc[mb][nb], 0, 0, 0);
    }

    #pragma unroll
    for (int nb = 0; nb < 4; ++nb) {
        const int n = bn + wn + nb * 16 + ln;
        const float bv = bias[n];
        #pragma unroll
        for (int mb = 0; mb < 4; ++mb) {
            const int m = bm + wm + mb * 16 + quad * 4;
            #pragma unroll
            for (int r = 0; r < 4; ++r)
                C[(size_t)(m + r) * 512 + n] = acc[mb][nb][r] + bv;
        }
    }
}

// ---------------- MFMA flash attention, register-weight MLP ----------------
// Block = (b, 16 queries, 8 heads); 4 waves, wave wv -> heads 2wv,2wv+1.
// MLP: lane owns units quad*8..+7 (w1/b1 slice in VGPRs); lane's 8 gelu
// outputs form an MFMA A-fragment; layer-2 (32->8 heads) is ONE mfma against
// a register-constant w2 B-fragment (alpha folded). D -> bias_s (double-
// buffered LDS, the only cross-wave handoff) -> QK consumer. coords/mask are
// per-lane global loads (no LDS staging). ONE barrier per j-tile.
#define BIAS_IDX(i, j, h) ((i) * 291 + (j) * 9 + (h))
__global__ __launch_bounds__(256, 2)
void attn_kernel(const unsigned short* __restrict__ Qb,
                 const unsigned short* __restrict__ Kb,
                 const unsigned short* __restrict__ Vt,
                 const float* __restrict__ coords,
                 const unsigned char* __restrict__ mask,
                 const float* __restrict__ w1, const float* __restrict__ b1,
                 const float* __restrict__ w2, const float* __restrict__ b2,
                 const float* __restrict__ coord_scales,
                 const float* __restrict__ alpha_p,
                 unsigned short* __restrict__ attn_out) {
    const int b   = blockIdx.y;
    const int i0  = blockIdx.x * TI;
    const int tid = threadIdx.x;
    const int wv  = tid >> 6;
    const int lane = tid & 63;
    const int quad = lane >> 4;
    const int ln   = lane & 15;
    const int h0   = wv * 2;

    __shared__ float bias_s[2][TI * 291 + 9];                   // 2 x 18.65 KB
    __shared__ __align__(16) unsigned short ps[NHEAD][TI][40];  // 10 KB
    __shared__ float ci_s[TI][3];

    const float alpha = alpha_p[0];
    const float isx = 1.0f / coord_scales[0];
    const float isy = 1.0f / coord_scales[1];
    const float isz = 1.0f / coord_scales[2];

    if (tid < TI * 3)
        ci_s[tid / 3][tid % 3] =
            coords[((size_t)b * NN + i0 + tid / 3) * 3 + tid % 3] / coord_scales[tid % 3];

    // ---- per-lane MLP weight slice: units ku = quad*8+jj ----
    float4 w1r[8]; float b1r[8];
    #pragma unroll
    for (int jj = 0; jj < 8; ++jj) {
        w1r[jj] = *(const float4*)(w1 + (quad * 8 + jj) * 4);
        b1r[jj] = b1[quad * 8 + jj];
    }
    // w2 B-fragment: B[n=ln(head)][k=quad*8+jj] = alpha*w2, heads 8..15 -> 0
    short8 b2f;
    #pragma unroll
    for (int jj = 0; jj < 8; ++jj) {
        const float v = (ln < 8) ? alpha * w2[ln * 32 + quad * 8 + jj] : 0.0f;
        b2f[jj] = (short)f2bf(v);
    }
    const float ab2 = (ln < 8) ? alpha * b2[ln] : 0.0f;

    // Q A-fragments (bf16, pre-scaled by 0.125)
    short8 qf[2][2];
    #pragma unroll
    for (int hh = 0; hh < 2; ++hh)
        #pragma unroll
        for (int kd = 0; kd < 2; ++kd)
            qf[hh][kd] = *(const short8*)(Qb + ((size_t)b * NN + i0 + ln) * 512
                                          + (h0 + hh) * 64 + kd * 32 + quad * 8);

    floatx4 oacc[2][4];
    #pragma unroll
    for (int hh = 0; hh < 2; ++hh)
        #pragma unroll
        for (int nd = 0; nd < 4; ++nd)
            oacc[hh][nd] = (floatx4){0.f, 0.f, 0.f, 0.f};
    float l_part[2][4];
    #pragma unroll
    for (int hh = 0; hh < 2; ++hh)
        #pragma unroll
        for (int r = 0; r < 4; ++r) l_part[hh][r] = 0.f;

    const unsigned char* maskp = mask + (size_t)b * NN;
    float cjx[2], cjy[2], cjz[2];

    #define LOAD_CJ(tt_) do { const int tt = (tt_);                               \
        if (tt < NT) {                                                            \
            const float* cp0 = coords + ((size_t)b * NN + tt * TJ + ln) * 3;      \
            cjx[0] = cp0[0] * isx; cjy[0] = cp0[1] * isy; cjz[0] = cp0[2] * isz;  \
            cjx[1] = cp0[48] * isx; cjy[1] = cp0[49] * isy; cjz[1] = cp0[50] * isz; \
        } } while (0)

    // MLP for tile tt -> bias_s[tt&1]; 4 i-groups x 2 j-halves per wave.
    #define MLP_TILE(tt_) do { const int tt = (tt_);                              \
        if (tt < NT) {                                                            \
            float* bout = bias_s[tt & 1];                                         \
            const int j0m = tt * TJ;                                              \
            _Pragma("unroll")                                                     \
            for (int g = 0; g < 4; ++g) {                                         \
                const int i = wv * 4 + g;                                         \
                const float cix = ci_s[i][0], ciy = ci_s[i][1], ciz = ci_s[i][2]; \
                const bool irow0 = (i0 + i < NS);                                 \
                _Pragma("unroll")                                                 \
                for (int jh = 0; jh < 2; ++jh) {                                  \
                    const float dx = cix - cjx[jh];                               \
                    const float dy = ciy - cjy[jh];                               \
                    const float dz = ciz - cjz[jh];                               \
                    const float dist = sqrtf(dx * dx + dy * dy + dz * dz);        \
                    short8 hf;                                                    \
                    _Pragma("unroll")                                             \
                    for (int jj = 0; jj < 8; ++jj) {                              \
                        const float4 wa = w1r[jj];                                \
                        float hu = fmaf(wa.x, dx, fmaf(wa.y, dy,                  \
                                   fmaf(wa.z, dz, fmaf(wa.w, dist, b1r[jj]))));   \
                        hu = gelu_fast(hu);                                       \
                        hf[jj] = (short)f2bf(hu);                                 \
                    }                                                             \
                    floatx4 D = __builtin_amdgcn_mfma_f32_16x16x32_bf16(          \
                        hf, b2f, (floatx4){0.f, 0.f, 0.f, 0.f}, 0, 0, 0);         \
                    if (ln < 8) {                                                 \
                        _Pragma("unroll")                                         \
                        for (int r = 0; r < 4; ++r) {                             \
                            const int jw = jh * 16 + quad * 4 + r;                \
                            const float val = (irow0 || (j0m + jw < NS))          \
                                              ? 0.0f : (D[r] + ab2);              \
                            bout[BIAS_IDX(i, jw, ln)] = val;                      \
                        }                                                         \
                    }                                                             \
                }                                                                 \
            }                                                                     \
        } } while (0)

    // ---- prologue ----
    __syncthreads();              // ci_s ready
    LOAD_CJ(0);
    MLP_TILE(0);
    __syncthreads();              // bias_s[0] ready

    for (int jt = 0; jt < NT; ++jt) {
        const int j0 = jt * TJ;
        const int pb = jt & 1;

        // ---- K/V/mask global loads for tile jt (fly under MLP) ----
        short8 kf[2][4], vf[2][4];
        #pragma unroll
        for (int hh = 0; hh < 2; ++hh) {
            const unsigned short* kbase = Kb + ((size_t)b * NN + j0) * 512 + (h0 + hh) * 64;
            kf[hh][0] = *(const short8*)(kbase + (size_t)ln * 512 + quad * 8);
            kf[hh][1] = *(const short8*)(kbase + (size_t)ln * 512 + 32 + quad * 8);
            kf[hh][2] = *(const short8*)(kbase + (size_t)(16 + ln) * 512 + quad * 8);
            kf[hh][3] = *(const short8*)(kbase + (size_t)(16 + ln) * 512 + 32 + quad * 8);
            const unsigned short* vbase = Vt + ((size_t)b * 512 + (h0 + hh) * 64) * NN + j0 + quad * 8;
            #pragma unroll
            for (int nd = 0; nd < 4; ++nd)
                vf[hh][nd] = *(const short8*)(vbase + (size_t)(nd * 16 + ln) * NN);
        }
        const unsigned char mm0 = maskp[j0 + ln];
        const unsigned char mm1 = maskp[j0 + 16 + ln];

        // ---- MLP for tile jt+1 -> bias_s[(jt+1)&1] ----
        LOAD_CJ(jt + 1);
        MLP_TILE(jt + 1);

        // ---- QK mfma + bias + exp -> ps (reads bias_s[jt&1]; within-wave ps) ----
        #pragma unroll
        for (int hh = 0; hh < 2; ++hh) {
            const int h = h0 + hh;
            floatx4 s0 = (floatx4){0.f, 0.f, 0.f, 0.f};
            floatx4 s1 = (floatx4){0.f, 0.f, 0.f, 0.f};
            s0 = __builtin_amdgcn_mfma_f32_16x16x32_bf16(qf[hh][0], kf[hh][0], s0, 0, 0, 0);
            s0 = __builtin_amdgcn_mfma_f32_16x16x32_bf16(qf[hh][1], kf[hh][1], s0, 0, 0, 0);
            s1 = __builtin_amdgcn_mfma_f32_16x16x32_bf16(qf[hh][0], kf[hh][2], s1, 0, 0, 0);
            s1 = __builtin_amdgcn_mfma_f32_16x16x32_bf16(qf[hh][1], kf[hh][3], s1, 0, 0, 0);
            #pragma unroll
            for (int r = 0; r < 4; ++r) {
                const int row = quad * 4 + r;
                float v0 = s0[r] + bias_s[pb][BIAS_IDX(row, ln, h)];
                float v1 = s1[r] + bias_s[pb][BIAS_IDX(row, 16 + ln, h)];
                v0 = mm0 ? -1e30f : v0;
                v1 = mm1 ? -1e30f : v1;
                const float e0 = __expf(v0 - FIX_M);
                const float e1 = __expf(v1 - FIX_M);
                l_part[hh][r] += e0 + e1;
                ps[h][row][ln]      = f2bf(e0);
                ps[h][row][16 + ln] = f2bf(e1);
            }
        }

        // ---- PV mfma (ps read is within-wave) ----
        #pragma unroll
        for (int hh = 0; hh < 2; ++hh) {
            const int h = h0 + hh;
            short8 pa = *(const short8*)&ps[h][ln][quad * 8];
            #pragma unroll
            for (int nd = 0; nd < 4; ++nd)
                oacc[hh][nd] = __builtin_amdgcn_mfma_f32_16x16x32_bf16(pa, vf[hh][nd], oacc[hh][nd], 0, 0, 0);
        }

        __syncthreads();   // single barrier: bias_s[(jt+1)&1] ready; QK(jt) reads done
    }

    // epilogue: reduce l over 16 lanes per row, O /= l, store bf16
    #pragma unroll
    for (int hh = 0; hh < 2; ++hh) {
        float rl[4];
        #pragma unroll
        for (int r = 0; r < 4; ++r) {
            float l = l_part[hh][r];
            l += __shfl_xor(l, 1, 64);
            l += __shfl_xor(l, 2, 64);
            l += __shfl_xor(l, 4, 64);
            l += __shfl_xor(l, 8, 64);
            rl[r] = 1.0f / l;
        }
        #pragma unroll
        for (int nd = 0; nd < 4; ++nd)
            #pragma unroll
            for (int r = 0; r < 4; ++r)
                attn_out[((size_t)b * NN + i0 + quad * 4 + r) * 512
                         + (h0 + hh) * 64 + nd * 16 + ln] = f2bf(oacc[hh][nd][r] * rl[r]);
    }
    #undef LOAD_CJ
    #undef MLP_TILE
}

extern "C" void kernel_launch(void* const* d_in, const int* in_sizes, int n_in,
                              void* d_out, int out_size, void* d_ws, size_t ws_size,
                              hipStream_t stream) {
    const float* x        = (const float*)d_in[0];
    const float* coords   = (const float*)d_in[1];
    const unsigned char* kpm = (const unsigned char*)d_in[2];
    const float* qkv_w    = (const float*)d_in[3];
    const float* out_w    = (const float*)d_in[4];
    const float* out_b    = (const float*)d_in[5];
    const float* alpha    = (const float*)d_in[6];
    const float* w1       = (const float*)d_in[7];
    const float* b1       = (const float*)d_in[8];
    const float* w2       = (const float*)d_in[9];
    const float* b2       = (const float*)d_in[10];
    const float* cscales  = (const float*)d_in[11];
    float* out = (float*)d_out;

    const int M = BB * NN;
    unsigned short* Qb = (unsigned short*)d_ws;
    unsigned short* Kb = Qb + (size_t)M * D_MODEL;
    unsigned short* Vt = Kb + (size_t)M * D_MODEL;
    unsigned short* Ao = Vt + (size_t)M * D_MODEL;

    {
        dim3 grid(3 * D_MODEL / 128, M / 128);
        gemm_qkv_mfma<<<grid, 256, 0, stream>>>(x, qkv_w, Qb, Kb, Vt);
    }
    {
        dim3 grid(NN / TI, BB);
        attn_kernel<<<grid, 256, 0, stream>>>(Qb, Kb, Vt, coords, kpm, w1, b1, w2, b2,
                                              cscales, alpha, Ao);
    }
    {
        dim3 grid(D_MODEL / 128, M / 128);
        gemm_out_mfma<<<grid, 256, 0, stream>>>(Ao, out_w, out_b, out);
    }
}